// Round 1
// baseline (3302.304 us; speedup 1.0000x reference)
//
#include <hip/hip_runtime.h>
#include <math.h>

// VecPointNet on MI355X, round 1: correct fp32 implementation.
// ws layout (bytes):
//   [0, 1MB)            idx   int32 (B,N,16)
//   [1MB, +25.17MB)     hA    (B,N,3,128)  point-major, comp-major-over-h
//   [.., +25.17MB)      hB
//   [.., +25.17MB)      acc   out accumulation, same layout (j = c*128+cd)
//   [.., +12KB)         g     (B, 3*128) sums over N
// total ~73 MB.

#define EPSV 1e-12f

// ---------------------------------------------------------------- KNN
__global__ __launch_bounds__(128) void knn_kernel(const float* __restrict__ x,
                                                  int* __restrict__ idx) {
    __shared__ float px[2048], py[2048], pz[2048];
    int b = blockIdx.x;
    int nq = blockIdx.y * 128 + threadIdx.x;
    for (int i = threadIdx.x; i < 2048; i += 128) {
        px[i] = x[b * 6144 + i];
        py[i] = x[b * 6144 + 2048 + i];
        pz[i] = x[b * 6144 + 4096 + i];
    }
    __syncthreads();
    float qx = px[nq], qy = py[nq], qz = pz[nq];
    // exact same fp32 op order as numpy ref: ((x*x)+(y*y))+(z*z), no fma
    float sqn = __fadd_rn(__fadd_rn(__fmul_rn(qx, qx), __fmul_rn(qy, qy)), __fmul_rn(qz, qz));
    float dl[16];
    int il[16];
#pragma unroll
    for (int j = 0; j < 16; ++j) { dl[j] = INFINITY; il[j] = 0; }
    for (int m = 0; m < 2048; ++m) {
        float mx = px[m], my = py[m], mz = pz[m];
        float sqm = __fadd_rn(__fadd_rn(__fmul_rn(mx, mx), __fmul_rn(my, my)), __fmul_rn(mz, mz));
        float dot = __fadd_rn(__fadd_rn(__fmul_rn(qx, mx), __fmul_rn(qy, my)), __fmul_rn(qz, mz));
        float d2 = __fsub_rn(__fadd_rn(sqn, sqm), __fmul_rn(2.0f, dot));
        if (d2 < dl[15]) {  // strict < keeps earlier index on ties (stable top_k)
#pragma unroll
            for (int j = 15; j >= 1; --j) {
                bool sh = d2 < dl[j - 1];
                float nd = sh ? dl[j - 1] : d2;
                int ni = sh ? il[j - 1] : m;
                bool up = d2 < dl[j];
                dl[j] = up ? nd : dl[j];
                il[j] = up ? ni : il[j];
            }
            if (d2 < dl[0]) { dl[0] = d2; il[0] = m; }
        }
    }
#pragma unroll
    for (int j = 0; j < 16; ++j) idx[(b * 2048 + nq) * 16 + j] = il[j];
}

// ---------------------------------------------------------------- stage 1
// one block per point. phases: (a) v' for all 16 nbrs  (b) Wd GEMM over 48
// cols (16k x 3c) with transposed chunk-rotated weight tiles  (c) act+pool.
__global__ __launch_bounds__(256) void stage1_kernel(const float* __restrict__ x,
                                                     const int* __restrict__ idx,
                                                     const float* __restrict__ Win,
                                                     const float* __restrict__ Wd,
                                                     float* __restrict__ hout) {
    __shared__ float wdT[64 * 128];  // reused as comb[8][128][3] in phase C
    __shared__ float vb[128 * 50];   // v' [h][col], col=k*3+c, row stride 50
    __shared__ float red[4];
    int t = threadIdx.x;
    int bid = blockIdx.x;
    int b = bid >> 11, n = bid & 2047;
    int gpt = b * 2048 + n;

    // ---- phase A: v' = channel_equi_vec_normalize(W_in @ y) per neighbor
    {
        int h = t & 127, kk = t >> 7;
        float w0 = Win[h * 3], w1 = Win[h * 3 + 1], w2 = Win[h * 3 + 2];
        float pxv = x[b * 6144 + n], pyv = x[b * 6144 + 2048 + n], pzv = x[b * 6144 + 4096 + n];
        float pn = sqrtf(pxv * pxv + pyv * pyv + pzv * pzv);
        float inv = 1.f / fmaxf(pn, EPSV);
        float dx = pxv * inv, dy = pyv * inv, dz = pzv * inv;
        for (int k = kk; k < 16; k += 2) {
            int m = idx[gpt * 16 + k];
            float qx = x[b * 6144 + m], qy = x[b * 6144 + 2048 + m], qz = x[b * 6144 + 4096 + m];
            float c0x = dy * qz - dz * qy, c0y = dz * qx - dx * qz, c0z = dx * qy - dy * qx;
            float vx = w0 * c0x + w1 * (qx - pxv) + w2 * pxv;
            float vy = w0 * c0y + w1 * (qy - pyv) + w2 * pyv;
            float vz = w0 * c0z + w1 * (qz - pzv) + w2 * pzv;
            float nh2 = vx * vx + vy * vy + vz * vz;
            float nh = sqrtf(nh2);
            float s = nh2;
#pragma unroll
            for (int off = 32; off; off >>= 1) s += __shfl_down(s, off, 64);
            if ((t & 63) == 0) red[t >> 6] = s;
            __syncthreads();
            float T = red[kk * 2] + red[kk * 2 + 1];
            float scale = (nh / fmaxf(nh, EPSV)) / fmaxf(sqrtf(T), EPSV);
            vb[h * 50 + k * 3 + 0] = vx * scale;
            vb[h * 50 + k * 3 + 1] = vy * scale;
            vb[h * 50 + k * 3 + 2] = vz * scale;
            __syncthreads();
        }
    }

    // ---- phase B: K = Wd @ v'   (128h x 128j) x (j x 48cols)
    int hgrp = t & 31, cgrp = t >> 5;
    int h0 = hgrp * 4, c0 = cgrp * 6;
    float acc[4][2][3];
#pragma unroll
    for (int a = 0; a < 4; ++a)
#pragma unroll
        for (int kk = 0; kk < 2; ++kk)
#pragma unroll
            for (int c = 0; c < 3; ++c) acc[a][kk][c] = 0.f;

    for (int half = 0; half < 2; ++half) {
        __syncthreads();
        // stage wdT[jl][h] = Wd[h][half*64+jl], 16B-chunk rotated by jl
        for (int i = t; i < 8192; i += 256) {
            int hh = i >> 6, jl = i & 63;
            wdT[jl * 128 + (((hh >> 2) + jl) & 31) * 4 + (hh & 3)] = Wd[hh * 128 + half * 64 + jl];
        }
        __syncthreads();
#pragma unroll 2
        for (int jl = 0; jl < 64; ++jl) {
            int j = half * 64 + jl;
            float4 wv = *(const float4*)&wdT[jl * 128 + ((hgrp + jl) & 31) * 4];
            float2 v01 = *(const float2*)&vb[j * 50 + c0];
            float2 v23 = *(const float2*)&vb[j * 50 + c0 + 2];
            float2 v45 = *(const float2*)&vb[j * 50 + c0 + 4];
            float vv0[3] = {v01.x, v01.y, v23.x};
            float vv1[3] = {v23.y, v45.x, v45.y};
            float wa[4] = {wv.x, wv.y, wv.z, wv.w};
#pragma unroll
            for (int a = 0; a < 4; ++a)
#pragma unroll
                for (int c = 0; c < 3; ++c) {
                    acc[a][0][c] += wa[a] * vv0[c];
                    acc[a][1][c] += wa[a] * vv1[c];
                }
        }
    }

    // ---- phase C: VN-act, pool over k, combine over cgrp
    __syncthreads();
    float part[4][3];
#pragma unroll
    for (int a = 0; a < 4; ++a)
#pragma unroll
        for (int c = 0; c < 3; ++c) part[a][c] = 0.f;
#pragma unroll
    for (int a = 0; a < 4; ++a)
#pragma unroll
        for (int kk = 0; kk < 2; ++kk) {
            float kx = acc[a][kk][0], ky = acc[a][kk][1], kz = acc[a][kk][2];
            float kn = sqrtf(kx * kx + ky * ky + kz * kz);
            float ki = 1.f / fmaxf(kn, EPSV);
            float kdx = kx * ki, kdy = ky * ki, kdz = kz * ki;
            int h = h0 + a, k = cgrp * 2 + kk;
            float ux = vb[h * 50 + k * 3], uy = vb[h * 50 + k * 3 + 1], uz = vb[h * 50 + k * 3 + 2];
            float dot = ux * kdx + uy * kdy + uz * kdz;
            float delta = (dot >= 0.f) ? 0.f : -dot;
            part[a][0] += ux + delta * kdx;
            part[a][1] += uy + delta * kdy;
            part[a][2] += uz + delta * kdz;
        }
    float* comb = wdT;
#pragma unroll
    for (int a = 0; a < 4; ++a)
#pragma unroll
        for (int c = 0; c < 3; ++c) comb[cgrp * 384 + (h0 + a) * 3 + c] = part[a][c];
    __syncthreads();
    if (t < 128) {
#pragma unroll
        for (int c = 0; c < 3; ++c) {
            float s = 0.f;
#pragma unroll
            for (int cg = 0; cg < 8; ++cg) s += comb[cg * 384 + t * 3 + c];
            hout[(size_t)gpt * 384 + c * 128 + t] = s * (1.f / 16.f);
        }
    }
}

// ---------------------------------------------------------------- layer helpers
__device__ __forceinline__ void stage_rows(float* wbuf, const float* __restrict__ src,
                                           int row_stride, int col0) {
    // wbuf[h][jl] rotated by h: wbuf[h*64 + ((jl+h)&63)]
    for (int i = threadIdx.x; i < 8192; i += 256) {
        int h = i >> 6, jl = i & 63;
        wbuf[h * 64 + ((jl + h) & 63)] = src[h * row_stride + col0 + jl];
    }
}

__device__ __forceinline__ void gemm_part(const float* wbuf, const float* u, int h, int p0,
                                          int jbase, float acc[4][3]) {
    // acc[pi][c] += sum_jl w[h][jl] * u[(p0+pi)*384 + c*128 + jbase+jl]
#pragma unroll 2
    for (int jl = 0; jl < 64; jl += 4) {
        float a0 = wbuf[h * 64 + ((jl + 0 + h) & 63)];
        float a1 = wbuf[h * 64 + ((jl + 1 + h) & 63)];
        float a2 = wbuf[h * 64 + ((jl + 2 + h) & 63)];
        float a3 = wbuf[h * 64 + ((jl + 3 + h) & 63)];
#pragma unroll
        for (int pi = 0; pi < 4; ++pi)
#pragma unroll
            for (int c = 0; c < 3; ++c) {
                float4 v = *(const float4*)&u[(p0 + pi) * 384 + c * 128 + jbase + jl];
                acc[pi][c] += a0 * v.x + a1 * v.y + a2 * v.z + a3 * v.w;
            }
    }
}

__device__ __forceinline__ void gemm_part_g(const float* wbuf, const float* gbuf, int h,
                                            int jbase, float accg[3]) {
#pragma unroll 2
    for (int jl = 0; jl < 64; jl += 4) {
        float a0 = wbuf[h * 64 + ((jl + 0 + h) & 63)];
        float a1 = wbuf[h * 64 + ((jl + 1 + h) & 63)];
        float a2 = wbuf[h * 64 + ((jl + 2 + h) & 63)];
        float a3 = wbuf[h * 64 + ((jl + 3 + h) & 63)];
#pragma unroll
        for (int c = 0; c < 3; ++c) {
            float4 v = *(const float4*)&gbuf[c * 128 + jbase + jl];
            accg[c] += a0 * v.x + a1 * v.y + a2 * v.z + a3 * v.w;
        }
    }
}

struct NormOut {
    float vp[4][3];
};

// ---------------------------------------------------------------- layer A
__global__ __launch_bounds__(256) void layerA_kernel(const float* __restrict__ hin,
                                                     const float* __restrict__ Wsl,
                                                     const float* __restrict__ Wdsl,
                                                     float* __restrict__ hout,
                                                     float* __restrict__ g) {
    __shared__ float wbuf[128 * 64];
    __shared__ float u[8 * 3 * 128];
    __shared__ float red4[4][4];
    int t = threadIdx.x, h = t & 127, ph = t >> 7;
    int bid = blockIdx.x, b = bid >> 8, n0 = (bid & 255) * 8;
    int p0 = ph * 4;
    size_t base = (size_t)(b * 2048 + n0) * 384;
    for (int i = t; i < 3072; i += 256) u[i] = hin[base + i];
    __syncthreads();

    float acc[4][3];
#pragma unroll
    for (int pi = 0; pi < 4; ++pi)
#pragma unroll
        for (int c = 0; c < 3; ++c) acc[pi][c] = 0.f;
    stage_rows(wbuf, Wsl, 128, 0);
    __syncthreads();
    gemm_part(wbuf, u, h, p0, 0, acc);
    __syncthreads();
    stage_rows(wbuf, Wsl, 128, 64);
    __syncthreads();
    gemm_part(wbuf, u, h, p0, 64, acc);

    // normalize per point (channel_equi_vec_normalize)
    float sl[4], nhv[4], vp[4][3];
#pragma unroll
    for (int pi = 0; pi < 4; ++pi) {
        sl[pi] = acc[pi][0] * acc[pi][0] + acc[pi][1] * acc[pi][1] + acc[pi][2] * acc[pi][2];
        nhv[pi] = sqrtf(sl[pi]);
    }
#pragma unroll
    for (int off = 32; off; off >>= 1)
#pragma unroll
        for (int pi = 0; pi < 4; ++pi) sl[pi] += __shfl_down(sl[pi], off, 64);
    int wv = t >> 6;
    if ((t & 63) == 0) {
#pragma unroll
        for (int pi = 0; pi < 4; ++pi) red4[wv][pi] = sl[pi];
    }
    __syncthreads();
#pragma unroll
    for (int pi = 0; pi < 4; ++pi) {
        float T = red4[2 * ph][pi] + red4[2 * ph + 1][pi];
        float sc = (nhv[pi] / fmaxf(nhv[pi], EPSV)) / fmaxf(sqrtf(T), EPSV);
#pragma unroll
        for (int c = 0; c < 3; ++c) vp[pi][c] = acc[pi][c] * sc;
    }
    __syncthreads();  // all GEMM1/red reads done -> safe to overwrite u
#pragma unroll
    for (int pi = 0; pi < 4; ++pi)
#pragma unroll
        for (int c = 0; c < 3; ++c) u[(p0 + pi) * 384 + c * 128 + h] = vp[pi][c];
    __syncthreads();

    float acc2[4][3];
#pragma unroll
    for (int pi = 0; pi < 4; ++pi)
#pragma unroll
        for (int c = 0; c < 3; ++c) acc2[pi][c] = 0.f;
    stage_rows(wbuf, Wdsl, 128, 0);
    __syncthreads();
    gemm_part(wbuf, u, h, p0, 0, acc2);
    __syncthreads();
    stage_rows(wbuf, Wdsl, 128, 64);
    __syncthreads();
    gemm_part(wbuf, u, h, p0, 64, acc2);

    float gx = 0.f, gy = 0.f, gz = 0.f;
#pragma unroll
    for (int pi = 0; pi < 4; ++pi) {
        float kx = acc2[pi][0], ky = acc2[pi][1], kz = acc2[pi][2];
        float kn = sqrtf(kx * kx + ky * ky + kz * kz);
        float ki = 1.f / fmaxf(kn, EPSV);
        float kdx = kx * ki, kdy = ky * ki, kdz = kz * ki;
        float dot = vp[pi][0] * kdx + vp[pi][1] * kdy + vp[pi][2] * kdz;
        float delta = (dot >= 0.f) ? 0.f : -dot;
        float o0 = vp[pi][0] + delta * kdx;
        float o1 = vp[pi][1] + delta * kdy;
        float o2 = vp[pi][2] + delta * kdz;
        size_t gp = (size_t)(b * 2048 + n0 + p0 + pi) * 384;
        hout[gp + h] = o0;
        hout[gp + 128 + h] = o1;
        hout[gp + 256 + h] = o2;
        gx += o0; gy += o1; gz += o2;
    }
    atomicAdd(&g[b * 384 + h], gx);
    atomicAdd(&g[b * 384 + 128 + h], gy);
    atomicAdd(&g[b * 384 + 256 + h], gz);
}

// ---------------------------------------------------------------- layer B
__global__ __launch_bounds__(256) void layerB_kernel(const float* __restrict__ hin,
                                                     const float* __restrict__ g,
                                                     const float* __restrict__ Gsl,
                                                     const float* __restrict__ Gdsl,
                                                     const float* __restrict__ Woutl,
                                                     float* __restrict__ hnext,
                                                     float* __restrict__ oacc) {
    __shared__ float wbuf[128 * 64];
    __shared__ float u[8 * 3 * 128];
    __shared__ float gbuf[384];
    __shared__ float red4[4][4];
    int t = threadIdx.x, h = t & 127, ph = t >> 7;
    int bid = blockIdx.x, b = bid >> 8, n0 = (bid & 255) * 8;
    int p0 = ph * 4;
    size_t base = (size_t)(b * 2048 + n0) * 384;
    for (int i = t; i < 3072; i += 256) u[i] = hin[base + i];
    for (int i = t; i < 384; i += 256) gbuf[i] = g[b * 384 + i] * (1.f / 2048.f);
    __syncthreads();

    float acc[4][3], accg[3] = {0.f, 0.f, 0.f};
#pragma unroll
    for (int pi = 0; pi < 4; ++pi)
#pragma unroll
        for (int c = 0; c < 3; ++c) acc[pi][c] = 0.f;
    stage_rows(wbuf, Gsl, 256, 0);
    __syncthreads();
    gemm_part(wbuf, u, h, p0, 0, acc);
    __syncthreads();
    stage_rows(wbuf, Gsl, 256, 64);
    __syncthreads();
    gemm_part(wbuf, u, h, p0, 64, acc);
    __syncthreads();
    stage_rows(wbuf, Gsl, 256, 128);
    __syncthreads();
    gemm_part_g(wbuf, gbuf, h, 0, accg);
    __syncthreads();
    stage_rows(wbuf, Gsl, 256, 192);
    __syncthreads();
    gemm_part_g(wbuf, gbuf, h, 64, accg);
#pragma unroll
    for (int pi = 0; pi < 4; ++pi)
#pragma unroll
        for (int c = 0; c < 3; ++c) acc[pi][c] += accg[c];

    float sl[4], nhv[4], vp[4][3];
#pragma unroll
    for (int pi = 0; pi < 4; ++pi) {
        sl[pi] = acc[pi][0] * acc[pi][0] + acc[pi][1] * acc[pi][1] + acc[pi][2] * acc[pi][2];
        nhv[pi] = sqrtf(sl[pi]);
    }
#pragma unroll
    for (int off = 32; off; off >>= 1)
#pragma unroll
        for (int pi = 0; pi < 4; ++pi) sl[pi] += __shfl_down(sl[pi], off, 64);
    int wv = t >> 6;
    if ((t & 63) == 0) {
#pragma unroll
        for (int pi = 0; pi < 4; ++pi) red4[wv][pi] = sl[pi];
    }
    __syncthreads();
#pragma unroll
    for (int pi = 0; pi < 4; ++pi) {
        float T = red4[2 * ph][pi] + red4[2 * ph + 1][pi];
        float sc = (nhv[pi] / fmaxf(nhv[pi], EPSV)) / fmaxf(sqrtf(T), EPSV);
#pragma unroll
        for (int c = 0; c < 3; ++c) vp[pi][c] = acc[pi][c] * sc;
    }
    __syncthreads();
#pragma unroll
    for (int pi = 0; pi < 4; ++pi)
#pragma unroll
        for (int c = 0; c < 3; ++c) u[(p0 + pi) * 384 + c * 128 + h] = vp[pi][c];
    __syncthreads();

    float acc2[4][3];
#pragma unroll
    for (int pi = 0; pi < 4; ++pi)
#pragma unroll
        for (int c = 0; c < 3; ++c) acc2[pi][c] = 0.f;
    stage_rows(wbuf, Gdsl, 128, 0);
    __syncthreads();
    gemm_part(wbuf, u, h, p0, 0, acc2);
    __syncthreads();
    stage_rows(wbuf, Gdsl, 128, 64);
    __syncthreads();
    gemm_part(wbuf, u, h, p0, 64, acc2);

    float op[4][3];
#pragma unroll
    for (int pi = 0; pi < 4; ++pi) {
        float kx = acc2[pi][0], ky = acc2[pi][1], kz = acc2[pi][2];
        float kn = sqrtf(kx * kx + ky * ky + kz * kz);
        float ki = 1.f / fmaxf(kn, EPSV);
        float kdx = kx * ki, kdy = ky * ki, kdz = kz * ki;
        float dot = vp[pi][0] * kdx + vp[pi][1] * kdy + vp[pi][2] * kdz;
        float delta = (dot >= 0.f) ? 0.f : -dot;
        op[pi][0] = vp[pi][0] + delta * kdx;
        op[pi][1] = vp[pi][1] + delta * kdy;
        op[pi][2] = vp[pi][2] + delta * kdz;
        size_t gp = (size_t)(b * 2048 + n0 + p0 + pi) * 384;
        hnext[gp + h] = op[pi][0];
        hnext[gp + 128 + h] = op[pi][1];
        hnext[gp + 256 + h] = op[pi][2];
    }
    __syncthreads();  // GEMM2 reads of u done -> overwrite with h2
#pragma unroll
    for (int pi = 0; pi < 4; ++pi)
#pragma unroll
        for (int c = 0; c < 3; ++c) u[(p0 + pi) * 384 + c * 128 + h] = op[pi][c];
    __syncthreads();

    float acc3[4][3];
#pragma unroll
    for (int pi = 0; pi < 4; ++pi)
#pragma unroll
        for (int c = 0; c < 3; ++c) acc3[pi][c] = 0.f;
    stage_rows(wbuf, Woutl, 512, 0);
    __syncthreads();
    gemm_part(wbuf, u, h, p0, 0, acc3);
    __syncthreads();
    stage_rows(wbuf, Woutl, 512, 64);
    __syncthreads();
    gemm_part(wbuf, u, h, p0, 64, acc3);
#pragma unroll
    for (int pi = 0; pi < 4; ++pi) {
        size_t gp = (size_t)(b * 2048 + n0 + p0 + pi) * 384;
#pragma unroll
        for (int c = 0; c < 3; ++c) oacc[gp + c * 128 + h] += acc3[pi][c];
    }
}

// ---------------------------------------------------------------- transpose + mean
__global__ __launch_bounds__(256) void out_kernel(const float* __restrict__ acc,
                                                  float* __restrict__ out1,
                                                  float* __restrict__ out0) {
    __shared__ float tile[64][33];
    int b = blockIdx.z, n0 = blockIdx.x * 64, j0 = blockIdx.y * 32;
    int t = threadIdx.x;
#pragma unroll
    for (int r = 0; r < 8; ++r) {
        int nf = (t >> 5) + r * 8, jf = t & 31;
        tile[nf][jf] = acc[(size_t)(b * 2048 + n0 + nf) * 384 + j0 + jf];
    }
    __syncthreads();
#pragma unroll
    for (int r = 0; r < 8; ++r) {
        int jf = (t >> 6) + r * 4, nf = t & 63;
        int j = j0 + jf;
        int ridx = (j & 127) * 3 + (j >> 7);  // (cd, comp) row
        out1[((size_t)b * 384 + ridx) * 2048 + n0 + nf] = tile[nf][jf];
    }
    if (t < 32) {
        float s = 0.f;
#pragma unroll
        for (int n = 0; n < 64; ++n) s += tile[n][t];
        int j = j0 + t;
        int ridx = (j & 127) * 3 + (j >> 7);
        atomicAdd(&out0[b * 384 + ridx], s * (1.f / 2048.f));
    }
}

// ---------------------------------------------------------------- launch
extern "C" void kernel_launch(void* const* d_in, const int* in_sizes, int n_in,
                              void* d_out, int out_size, void* d_ws, size_t ws_size,
                              hipStream_t stream) {
    const float* x    = (const float*)d_in[0];
    const float* Win  = (const float*)d_in[1];
    const float* Wdin = (const float*)d_in[2];
    const float* Ws   = (const float*)d_in[3];
    const float* Wds  = (const float*)d_in[4];
    const float* Gs   = (const float*)d_in[5];
    const float* Gds  = (const float*)d_in[6];
    const float* Wout = (const float*)d_in[7];

    float* out0 = (float*)d_out;        // (B,CD,3) = 3072
    float* out1 = out0 + 3072;          // (B,CD,3,N)

    char* ws = (char*)d_ws;
    int* idx = (int*)ws;                                   // 1 MB
    float* hA  = (float*)(ws + (1 << 20));                 // 25.17 MB
    float* hB  = hA + 6291456;
    float* acc = hB + 6291456;
    float* g   = acc + 6291456;                            // 12 KB

    hipMemsetAsync(acc, 0, (size_t)6291456 * 4, stream);
    hipMemsetAsync(out0, 0, (size_t)3072 * 4, stream);

    knn_kernel<<<dim3(8, 16), 128, 0, stream>>>(x, idx);
    stage1_kernel<<<16384, 256, 0, stream>>>(x, idx, Win, Wdin, hA);
    for (int l = 0; l < 4; ++l) {
        hipMemsetAsync(g, 0, (size_t)3072 * 4, stream);
        layerA_kernel<<<2048, 256, 0, stream>>>(hA, Ws + l * 16384, Wds + l * 16384, hB, g);
        layerB_kernel<<<2048, 256, 0, stream>>>(hB, g, Gs + l * 32768, Gds + l * 16384,
                                                Wout + l * 128, hA, acc);
    }
    out_kernel<<<dim3(32, 12, 8), 256, 0, stream>>>(acc, out1, out0);
}

// Round 3
// 1819.612 us; speedup vs baseline: 1.8148x; 1.8148x over previous
//
#include <hip/hip_runtime.h>
#include <math.h>

// VecPointNet on MI355X, round 3: round-2 structure with wout_gemm tile fix
// (4x12 thread tile; 4x24 overran the 96-col tile -> OOB LDS reads + cross-
// block races -> NaN).
// channel_equi_vec_normalize(v) == v / max(||v||_F, eps)  (uniform scale), so
//   stage1: k = Wd@v' = (Wd@Win)@Y * s  with Y = {cross, diff, x}  (rank-3)
//   layers: k = Wd@(W@h * s) = (Wd@W)@h * s  -> two independent GEMMs/layer.

#define EPSV 1e-12f

// ---------------------------------------------------------------- KNN
__global__ __launch_bounds__(128) void knn_kernel(const float* __restrict__ x,
                                                  int* __restrict__ idx) {
    __shared__ float px[2048], py[2048], pz[2048];
    int b = blockIdx.x;
    int nq = blockIdx.y * 128 + threadIdx.x;
    for (int i = threadIdx.x; i < 2048; i += 128) {
        px[i] = x[b * 6144 + i];
        py[i] = x[b * 6144 + 2048 + i];
        pz[i] = x[b * 6144 + 4096 + i];
    }
    __syncthreads();
    float qx = px[nq], qy = py[nq], qz = pz[nq];
    float sqn = __fadd_rn(__fadd_rn(__fmul_rn(qx, qx), __fmul_rn(qy, qy)), __fmul_rn(qz, qz));
    float dl[16];
    int il[16];
#pragma unroll
    for (int j = 0; j < 16; ++j) { dl[j] = INFINITY; il[j] = 0; }
    for (int m = 0; m < 2048; ++m) {
        float mx = px[m], my = py[m], mz = pz[m];
        float sqm = __fadd_rn(__fadd_rn(__fmul_rn(mx, mx), __fmul_rn(my, my)), __fmul_rn(mz, mz));
        float dot = __fadd_rn(__fadd_rn(__fmul_rn(qx, mx), __fmul_rn(qy, my)), __fmul_rn(qz, mz));
        float d2 = __fsub_rn(__fadd_rn(sqn, sqm), __fmul_rn(2.0f, dot));
        if (d2 < dl[15]) {
#pragma unroll
            for (int j = 15; j >= 1; --j) {
                bool sh = d2 < dl[j - 1];
                float nd = sh ? dl[j - 1] : d2;
                int ni = sh ? il[j - 1] : m;
                bool up = d2 < dl[j];
                dl[j] = up ? nd : dl[j];
                il[j] = up ? ni : il[j];
            }
            if (d2 < dl[0]) { dl[0] = d2; il[0] = m; }
        }
    }
#pragma unroll
    for (int j = 0; j < 16; ++j) idx[(b * 2048 + nq) * 16 + j] = il[j];
}

// ---------------------------------------------------------------- precompute
__global__ __launch_bounds__(256) void precompute_kernel(
    const float* __restrict__ Win, const float* __restrict__ Wdin,
    const float* __restrict__ Ws, const float* __restrict__ Wds,
    const float* __restrict__ Gs, const float* __restrict__ Gds,
    float* __restrict__ Wcat1, float* __restrict__ Wcat2, float* __restrict__ Wg,
    float* __restrict__ Mbuf, float* __restrict__ Gbuf) {
    __shared__ float row[128];
    int blk = blockIdx.x, t = threadIdx.x;
    if (blk < 512) {  // Q = Wds@Ws
        int l = blk >> 7, i = blk & 127;
        if (t < 128) row[t] = Wds[l * 16384 + i * 128 + t];
        __syncthreads();
        if (t < 128) {
            float acc = 0.f;
            for (int m = 0; m < 128; ++m) acc += row[m] * Ws[l * 16384 + m * 128 + t];
            Wcat1[l * 32768 + (128 + i) * 128 + t] = acc;
            Wcat1[l * 32768 + i * 128 + t] = Ws[l * 16384 + i * 128 + t];
        }
    } else if (blk < 1024) {  // R = Gds@Gs
        int l = (blk - 512) >> 7, i = (blk - 512) & 127;
        if (t < 128) row[t] = Gds[l * 16384 + i * 128 + t];
        __syncthreads();
        float acc = 0.f;
        for (int m = 0; m < 128; ++m) acc += row[m] * Gs[l * 32768 + m * 256 + t];
        if (t < 128) {
            Wcat2[l * 32768 + (128 + i) * 128 + t] = acc;
            Wcat2[l * 32768 + i * 128 + t] = Gs[l * 32768 + i * 256 + t];
        } else {
            Wg[l * 32768 + (128 + i) * 128 + (t - 128)] = acc;
            Wg[l * 32768 + i * 128 + (t - 128)] = Gs[l * 32768 + i * 256 + t];
        }
    } else {  // M = Wdin@Win, G = Win^T Win
        if (t < 128) {
            float a0 = 0.f, a1 = 0.f, a2 = 0.f;
            for (int m = 0; m < 128; ++m) {
                float w = Wdin[t * 128 + m];
                a0 += w * Win[m * 3];
                a1 += w * Win[m * 3 + 1];
                a2 += w * Win[m * 3 + 2];
            }
            Mbuf[t * 3] = a0; Mbuf[t * 3 + 1] = a1; Mbuf[t * 3 + 2] = a2;
        } else if (t < 137) {
            int q = t - 128, a = q / 3, bb = q - 3 * a;
            float acc = 0.f;
            for (int m = 0; m < 128; ++m) acc += Win[m * 3 + a] * Win[m * 3 + bb];
            Gbuf[q] = acc;
        }
    }
}

// ---------------------------------------------------------------- stage 1
__global__ __launch_bounds__(256) void stage1_kernel(
    const float* __restrict__ x, const int* __restrict__ idx,
    const float* __restrict__ Win, const float* __restrict__ Mbuf,
    const float* __restrict__ Gbuf, float* __restrict__ hout) {
    __shared__ float Yb[2][16][10];
    __shared__ float Pb[2][16][6];
    int t = threadIdx.x;
    int blk = blockIdx.x;
    int b = blk >> 10, n0 = (blk & 1023) * 2;
    if (t < 32) {
        int pt = t >> 4, k = t & 15;
        int n = n0 + pt, gpt = b * 2048 + n;
        float pxv = x[b * 6144 + n], pyv = x[b * 6144 + 2048 + n], pzv = x[b * 6144 + 4096 + n];
        float pn = sqrtf(pxv * pxv + pyv * pyv + pzv * pzv);
        float inv = 1.f / fmaxf(pn, EPSV);
        float dx = pxv * inv, dy = pyv * inv, dz = pzv * inv;
        int m = idx[gpt * 16 + k];
        float qx = x[b * 6144 + m], qy = x[b * 6144 + 2048 + m], qz = x[b * 6144 + 4096 + m];
        float Y[9];
        Y[0] = dy * qz - dz * qy; Y[1] = dz * qx - dx * qz; Y[2] = dx * qy - dy * qx;
        Y[3] = qx - pxv; Y[4] = qy - pyv; Y[5] = qz - pzv;
        Y[6] = pxv; Y[7] = pyv; Y[8] = pzv;
        float P[6];
        P[0] = Y[0] * Y[0] + Y[1] * Y[1] + Y[2] * Y[2];
        P[1] = Y[0] * Y[3] + Y[1] * Y[4] + Y[2] * Y[5];
        P[2] = Y[0] * Y[6] + Y[1] * Y[7] + Y[2] * Y[8];
        P[3] = Y[3] * Y[3] + Y[4] * Y[4] + Y[5] * Y[5];
        P[4] = Y[3] * Y[6] + Y[4] * Y[7] + Y[5] * Y[8];
        P[5] = Y[6] * Y[6] + Y[7] * Y[7] + Y[8] * Y[8];
        float nv2 = Gbuf[0] * P[0] + Gbuf[4] * P[3] + Gbuf[8] * P[5] +
                    (Gbuf[1] + Gbuf[3]) * P[1] + (Gbuf[2] + Gbuf[6]) * P[2] +
                    (Gbuf[5] + Gbuf[7]) * P[4];
        float s = 1.f / fmaxf(sqrtf(nv2), EPSV);
#pragma unroll
        for (int j = 0; j < 9; ++j) Yb[pt][k][j] = Y[j];
        Yb[pt][k][9] = s;
#pragma unroll
        for (int j = 0; j < 6; ++j) Pb[pt][k][j] = P[j];
    }
    __syncthreads();
    int pt = t >> 7, h = t & 127;
    int n = n0 + pt;
    float w0 = Win[h * 3], w1 = Win[h * 3 + 1], w2 = Win[h * 3 + 2];
    float m0 = Mbuf[h * 3], m1 = Mbuf[h * 3 + 1], m2 = Mbuf[h * 3 + 2];
    float cA0 = w0 * m0, cA3 = w1 * m1, cA5 = w2 * m2;
    float cA1 = w0 * m1 + w1 * m0, cA2 = w0 * m2 + w2 * m0, cA4 = w1 * m2 + w2 * m1;
    float cR0 = m0 * m0, cR3 = m1 * m1, cR5 = m2 * m2;
    float cR1 = 2.f * m0 * m1, cR2 = 2.f * m0 * m2, cR4 = 2.f * m1 * m2;
    float base[3] = {0.f, 0.f, 0.f}, corr[3] = {0.f, 0.f, 0.f};
    for (int k = 0; k < 16; ++k) {
        const float* Y = Yb[pt][k];
        const float* P = Pb[pt][k];
        float s = Y[9];
        float a = cA0 * P[0] + cA1 * P[1] + cA2 * P[2] + cA3 * P[3] + cA4 * P[4] + cA5 * P[5];
        float r2 = cR0 * P[0] + cR1 * P[1] + cR2 * P[2] + cR3 * P[3] + cR4 * P[4] + cR5 * P[5];
        float r = sqrtf(fmaxf(r2, 0.f));
        float D = fmaxf(s * r, EPSV);
        float dot = s * s * a / D;
        float wc = fmaxf(-dot, 0.f) * s / D;
#pragma unroll
        for (int c = 0; c < 3; ++c) {
            float yb = w0 * Y[c] + w1 * Y[3 + c] + w2 * Y[6 + c];
            float ym = m0 * Y[c] + m1 * Y[3 + c] + m2 * Y[6 + c];
            base[c] += s * yb;
            corr[c] += wc * ym;
        }
    }
#pragma unroll
    for (int c = 0; c < 3; ++c)
        hout[(size_t)(b * 2048 + n) * 384 + c * 128 + h] = (base[c] + corr[c]) * (1.f / 16.f);
}

// ---------------------------------------------------------------- layer GEMM
// C(256x48) = Wcat(256x128) @ Xtile(128x48), 16 pts/block, thread tile 4x12.
template <int MODE>
__global__ __launch_bounds__(256) void layer_gemm_kernel(
    const float* __restrict__ Xin, const float* __restrict__ Wcat,
    const float* __restrict__ biasbuf, float* __restrict__ Hout,
    float* __restrict__ g) {
    __shared__ float Xs[128 * 52];
    __shared__ float Wsb[16 * 260];
    int t = threadIdx.x;
    int blk = blockIdx.x;
    int b = blk >> 7, n0 = (blk & 127) * 16;
    const float* Xb = Xin + (size_t)(b * 2048 + n0) * 384;
    for (int i = t; i < 1536; i += 256) {
        int col = i >> 5, kq = i & 31;
        int p = col / 3, c = col - 3 * p;
        float4 v = *(const float4*)&Xb[p * 384 + c * 128 + 4 * kq];
        int k4 = 4 * kq;
        Xs[(k4 + 0) * 52 + col] = v.x;
        Xs[(k4 + 1) * 52 + col] = v.y;
        Xs[(k4 + 2) * 52 + col] = v.z;
        Xs[(k4 + 3) * 52 + col] = v.w;
    }
    int lane = t & 63, wv = t >> 6;
    int r0 = 4 * lane, c0 = 12 * wv;
    float acc[4][12];
#pragma unroll
    for (int rr = 0; rr < 4; ++rr)
#pragma unroll
        for (int cc = 0; cc < 12; ++cc) acc[rr][cc] = 0.f;

    for (int kc = 0; kc < 128; kc += 16) {
        __syncthreads();
        for (int i = t; i < 1024; i += 256) {
            int row = i & 255, kq = i >> 8;
            float4 v = *(const float4*)&Wcat[row * 128 + kc + 4 * kq];
            int k4 = 4 * kq;
            Wsb[(k4 + 0) * 260 + row] = v.x;
            Wsb[(k4 + 1) * 260 + row] = v.y;
            Wsb[(k4 + 2) * 260 + row] = v.z;
            Wsb[(k4 + 3) * 260 + row] = v.w;
        }
        __syncthreads();
#pragma unroll 8
        for (int k = 0; k < 16; ++k) {
            float4 w4 = *(const float4*)&Wsb[k * 260 + r0];
            float4 x0 = *(const float4*)&Xs[(kc + k) * 52 + c0];
            float4 x1 = *(const float4*)&Xs[(kc + k) * 52 + c0 + 4];
            float4 x2 = *(const float4*)&Xs[(kc + k) * 52 + c0 + 8];
            float wr[4] = {w4.x, w4.y, w4.z, w4.w};
            float xv[12] = {x0.x, x0.y, x0.z, x0.w, x1.x, x1.y, x1.z, x1.w,
                            x2.x, x2.y, x2.z, x2.w};
#pragma unroll
            for (int rr = 0; rr < 4; ++rr)
#pragma unroll
                for (int cc = 0; cc < 12; ++cc) acc[rr][cc] += wr[rr] * xv[cc];
        }
    }

    __syncthreads();
    if (lane >= 32) {
        int lr = 4 * (lane - 32);
#pragma unroll
        for (int rr = 0; rr < 4; ++rr)
#pragma unroll
            for (int cc = 0; cc < 12; ++cc) Xs[(lr + rr) * 52 + c0 + cc] = acc[rr][cc];
    }
    __syncthreads();

    if (lane < 32) {
        if (MODE == 1) {
#pragma unroll
            for (int c = 0; c < 3; ++c) {
                float4 bv = *(const float4*)&biasbuf[b * 768 + c * 256 + r0];
                float bb[4] = {bv.x, bv.y, bv.z, bv.w};
#pragma unroll
                for (int rr = 0; rr < 4; ++rr)
#pragma unroll
                    for (int pi = 0; pi < 4; ++pi) acc[rr][pi * 3 + c] += bb[rr];
            }
        }
        float psum[4];
#pragma unroll
        for (int pi = 0; pi < 4; ++pi) {
            float s = 0.f;
#pragma unroll
            for (int rr = 0; rr < 4; ++rr)
#pragma unroll
                for (int c = 0; c < 3; ++c) {
                    float vx = acc[rr][pi * 3 + c];
                    s += vx * vx;
                }
            psum[pi] = s;
        }
#pragma unroll
        for (int off = 16; off; off >>= 1)
#pragma unroll
            for (int pi = 0; pi < 4; ++pi) psum[pi] += __shfl_down(psum[pi], off, 32);
#pragma unroll
        for (int pi = 0; pi < 4; ++pi) psum[pi] = __shfl(psum[pi], 0, 32);

        float gsum[4][3];
        if (MODE == 0) {
#pragma unroll
            for (int rr = 0; rr < 4; ++rr)
#pragma unroll
                for (int c = 0; c < 3; ++c) gsum[rr][c] = 0.f;
        }
#pragma unroll
        for (int pi = 0; pi < 4; ++pi) {
            int p = 4 * wv + pi;
            float s = 1.f / fmaxf(sqrtf(psum[pi]), EPSV);
            float o[3][4];
#pragma unroll
            for (int rr = 0; rr < 4; ++rr) {
                float vx = acc[rr][pi * 3 + 0], vy = acc[rr][pi * 3 + 1], vz = acc[rr][pi * 3 + 2];
                float kx = Xs[(r0 + rr) * 52 + c0 + pi * 3 + 0];
                float ky = Xs[(r0 + rr) * 52 + c0 + pi * 3 + 1];
                float kz = Xs[(r0 + rr) * 52 + c0 + pi * 3 + 2];
                if (MODE == 1) {
                    kx += biasbuf[b * 768 + 0 * 256 + 128 + r0 + rr];
                    ky += biasbuf[b * 768 + 1 * 256 + 128 + r0 + rr];
                    kz += biasbuf[b * 768 + 2 * 256 + 128 + r0 + rr];
                }
                float kn = sqrtf(kx * kx + ky * ky + kz * kz);
                float D = fmaxf(s * kn, EPSV);
                float dot = s * s * (vx * kx + vy * ky + vz * kz) / D;
                float delta = fmaxf(-dot, 0.f);
                float f = delta * s / D;
                o[0][rr] = s * vx + f * kx;
                o[1][rr] = s * vy + f * ky;
                o[2][rr] = s * vz + f * kz;
            }
            size_t gp = (size_t)(b * 2048 + n0 + p) * 384;
#pragma unroll
            for (int c = 0; c < 3; ++c) {
                *(float4*)&Hout[gp + c * 128 + r0] = make_float4(o[c][0], o[c][1], o[c][2], o[c][3]);
                if (MODE == 0) {
#pragma unroll
                    for (int rr = 0; rr < 4; ++rr) gsum[rr][c] += o[c][rr];
                }
            }
        }
        if (MODE == 0) {
#pragma unroll
            for (int rr = 0; rr < 4; ++rr)
#pragma unroll
                for (int c = 0; c < 3; ++c)
                    atomicAdd(&g[b * 384 + c * 128 + r0 + rr], gsum[rr][c]);
        }
    }
}

// ---------------------------------------------------------------- gbias
__global__ __launch_bounds__(256) void gbias_kernel(const float* __restrict__ g,
                                                    const float* __restrict__ Wgl,
                                                    float* __restrict__ biasbuf) {
    __shared__ float gl[384];
    int b = blockIdx.x, r = threadIdx.x;
    for (int i = r; i < 384; i += 256) gl[i] = g[b * 384 + i] * (1.f / 2048.f);
    __syncthreads();
    float accv[3] = {0.f, 0.f, 0.f};
    const float4* wr = (const float4*)&Wgl[r * 128];
    for (int j = 0; j < 32; ++j) {
        float4 w4 = wr[j];
#pragma unroll
        for (int c = 0; c < 3; ++c) {
            float4 g4 = *(const float4*)&gl[c * 128 + 4 * j];
            accv[c] += w4.x * g4.x + w4.y * g4.y + w4.z * g4.z + w4.w * g4.w;
        }
    }
#pragma unroll
    for (int c = 0; c < 3; ++c) biasbuf[b * 768 + c * 256 + r] = accv[c];
}

// ---------------------------------------------------------------- Wout GEMM
// acc(128x96) += Wout_l(128x128, row stride 512) @ h2 tile. 32 pts/block,
// thread tile 4x12 (32 row-groups x 8 col-groups = 256 threads). [R2 BUGFIX]
__global__ __launch_bounds__(256) void wout_gemm_kernel(
    const float* __restrict__ Xin, const float* __restrict__ Wrow,
    float* __restrict__ accb) {
    __shared__ float Xs[128 * 100];
    __shared__ float Wsb[16 * 132];
    int t = threadIdx.x;
    int blk = blockIdx.x;
    int b = blk >> 6, n0 = (blk & 63) * 32;
    const float* Xb = Xin + (size_t)(b * 2048 + n0) * 384;
    for (int i = t; i < 3072; i += 256) {
        int col = i >> 5, kq = i & 31;
        int p = col / 3, c = col - 3 * p;
        float4 v = *(const float4*)&Xb[p * 384 + c * 128 + 4 * kq];
        int k4 = 4 * kq;
        Xs[(k4 + 0) * 100 + col] = v.x;
        Xs[(k4 + 1) * 100 + col] = v.y;
        Xs[(k4 + 2) * 100 + col] = v.z;
        Xs[(k4 + 3) * 100 + col] = v.w;
    }
    int r0 = 4 * (t & 31), c0 = 12 * (t >> 5);
    float acc[4][12];
#pragma unroll
    for (int rr = 0; rr < 4; ++rr)
#pragma unroll
        for (int cc = 0; cc < 12; ++cc) acc[rr][cc] = 0.f;

    for (int kc = 0; kc < 128; kc += 16) {
        __syncthreads();
        for (int i = t; i < 512; i += 256) {
            int row = i & 127, kq = i >> 7;
            float4 v = *(const float4*)&Wrow[row * 512 + kc + 4 * kq];
            int k4 = 4 * kq;
            Wsb[(k4 + 0) * 132 + row] = v.x;
            Wsb[(k4 + 1) * 132 + row] = v.y;
            Wsb[(k4 + 2) * 132 + row] = v.z;
            Wsb[(k4 + 3) * 132 + row] = v.w;
        }
        __syncthreads();
#pragma unroll 8
        for (int k = 0; k < 16; ++k) {
            float4 w4 = *(const float4*)&Wsb[k * 132 + r0];
            float4 x0 = *(const float4*)&Xs[(kc + k) * 100 + c0];
            float4 x1 = *(const float4*)&Xs[(kc + k) * 100 + c0 + 4];
            float4 x2 = *(const float4*)&Xs[(kc + k) * 100 + c0 + 8];
            float wr[4] = {w4.x, w4.y, w4.z, w4.w};
            float xv[12] = {x0.x, x0.y, x0.z, x0.w, x1.x, x1.y, x1.z, x1.w,
                            x2.x, x2.y, x2.z, x2.w};
#pragma unroll
            for (int rr = 0; rr < 4; ++rr)
#pragma unroll
                for (int cc = 0; cc < 12; ++cc) acc[rr][cc] += wr[rr] * xv[cc];
        }
    }
#pragma unroll
    for (int cc = 0; cc < 12; ++cc) {
        int col = c0 + cc;
        int p = col / 3, c = col - 3 * p;
        size_t gp = (size_t)(b * 2048 + n0 + p) * 384 + c * 128 + r0;
        float4 old = *(const float4*)&accb[gp];
        old.x += acc[0][cc]; old.y += acc[1][cc];
        old.z += acc[2][cc]; old.w += acc[3][cc];
        *(float4*)&accb[gp] = old;
    }
}

// ---------------------------------------------------------------- transpose + mean
__global__ __launch_bounds__(256) void out_kernel(const float* __restrict__ acc,
                                                  float* __restrict__ out1,
                                                  float* __restrict__ out0) {
    __shared__ float tile[64][33];
    int b = blockIdx.z, n0 = blockIdx.x * 64, j0 = blockIdx.y * 32;
    int t = threadIdx.x;
#pragma unroll
    for (int r = 0; r < 8; ++r) {
        int nf = (t >> 5) + r * 8, jf = t & 31;
        tile[nf][jf] = acc[(size_t)(b * 2048 + n0 + nf) * 384 + j0 + jf];
    }
    __syncthreads();
#pragma unroll
    for (int r = 0; r < 8; ++r) {
        int jf = (t >> 6) + r * 4, nf = t & 63;
        int j = j0 + jf;
        int ridx = (j & 127) * 3 + (j >> 7);
        out1[((size_t)b * 384 + ridx) * 2048 + n0 + nf] = tile[nf][jf];
    }
    if (t < 32) {
        float s = 0.f;
#pragma unroll
        for (int n = 0; n < 64; ++n) s += tile[n][t];
        int j = j0 + t;
        int ridx = (j & 127) * 3 + (j >> 7);
        atomicAdd(&out0[b * 384 + ridx], s * (1.f / 2048.f));
    }
}

// ---------------------------------------------------------------- launch
extern "C" void kernel_launch(void* const* d_in, const int* in_sizes, int n_in,
                              void* d_out, int out_size, void* d_ws, size_t ws_size,
                              hipStream_t stream) {
    const float* x    = (const float*)d_in[0];
    const float* Win  = (const float*)d_in[1];
    const float* Wdin = (const float*)d_in[2];
    const float* Ws   = (const float*)d_in[3];
    const float* Wds  = (const float*)d_in[4];
    const float* Gs   = (const float*)d_in[5];
    const float* Gds  = (const float*)d_in[6];
    const float* Wout = (const float*)d_in[7];

    float* out0 = (float*)d_out;   // (B,CD,3) = 3072
    float* out1 = out0 + 3072;     // (B,CD,3,N)

    char* ws = (char*)d_ws;
    int* idx = (int*)ws;                               // 1 MB
    float* hA   = (float*)(ws + (1 << 20));            // 6291456 floats
    float* hB   = hA + 6291456;
    float* acc  = hB + 6291456;
    float* g    = acc + 6291456;                       // 3072
    float* Wcat1 = g + 3072;                           // 4*32768
    float* Wcat2 = Wcat1 + 131072;
    float* Wg    = Wcat2 + 131072;
    float* Mbuf  = Wg + 131072;                        // 384
    float* Gbuf  = Mbuf + 384;                         // 16
    float* biasbuf = Gbuf + 16;                        // 6144

    hipMemsetAsync(acc, 0, (size_t)6291456 * 4, stream);
    hipMemsetAsync(out0, 0, (size_t)3072 * 4, stream);

    knn_kernel<<<dim3(8, 16), 128, 0, stream>>>(x, idx);
    precompute_kernel<<<1025, 256, 0, stream>>>(Win, Wdin, Ws, Wds, Gs, Gds,
                                                Wcat1, Wcat2, Wg, Mbuf, Gbuf);
    stage1_kernel<<<8192, 256, 0, stream>>>(x, idx, Win, Mbuf, Gbuf, hA);
    for (int l = 0; l < 4; ++l) {
        hipMemsetAsync(g, 0, (size_t)3072 * 4, stream);
        layer_gemm_kernel<0><<<1024, 256, 0, stream>>>(hA, Wcat1 + l * 32768, nullptr, hB, g);
        gbias_kernel<<<8, 256, 0, stream>>>(g, Wg + l * 32768, biasbuf);
        layer_gemm_kernel<1><<<1024, 256, 0, stream>>>(hB, Wcat2 + l * 32768, biasbuf, hA, nullptr);
        wout_gemm_kernel<<<512, 256, 0, stream>>>(hA, Wout + l * 128, acc);
    }
    out_kernel<<<dim3(32, 12, 8), 256, 0, stream>>>(acc, out1, out0);
}

// Round 5
// 908.044 us; speedup vs baseline: 3.6367x; 2.0039x over previous
//
#include <hip/hip_runtime.h>
#include <math.h>

// VecPointNet on MI355X, round 5: double-bf16 (hi/lo) MFMA GEMMs.
// W@X ~= Whi@Xhi + Whi@Xlo + Wlo@Xhi (fp32 acc) -> rel err ~5e-6, vs 4e-3 for
// plain bf16 (round 4 failed at 9.7e-2 = 24x amplification of 4e-3).
// K-loops read A/B fragments straight from global (L1/L2-resident, 16B/lane
// contiguous) -> no LDS, no barriers in the K-loop. LDS only for epilogue.

#define EPSV 1e-12f

typedef unsigned short us;
typedef __attribute__((ext_vector_type(8))) short short8;
typedef __attribute__((ext_vector_type(4))) float f32x4;

__device__ __forceinline__ us f2bf(float f) {
    unsigned int u = __float_as_uint(f);
    unsigned int r = (u + 0x7FFFu + ((u >> 16) & 1u)) >> 16;
    return (us)r;
}
__device__ __forceinline__ float bf2f(us s) {
    return __uint_as_float(((unsigned int)s) << 16);
}
__device__ __forceinline__ void wsplit(float v, us* __restrict__ hi, us* __restrict__ lo,
                                       size_t o) {
    us h = f2bf(v);
    hi[o] = h;
    lo[o] = f2bf(v - bf2f(h));
}

// ---------------------------------------------------------------- KNN
// 8 threads per query, 32 queries/block, 512 blocks. Same fp32 d2 arithmetic
// as numpy; merge tie-breaks by (d2, index) to match stable top_k.
__global__ __launch_bounds__(256) void knn_kernel(const float* __restrict__ x,
                                                  int* __restrict__ idx) {
    __shared__ float px[2048], py[2048], pz[2048];
    __shared__ float md[32][8][17];
    __shared__ int mi[32][8][17];
    int t = threadIdx.x;
    int b = blockIdx.y, q0 = blockIdx.x * 32;
    for (int i = t; i < 2048; i += 256) {
        px[i] = x[b * 6144 + i];
        py[i] = x[b * 6144 + 2048 + i];
        pz[i] = x[b * 6144 + 4096 + i];
    }
    __syncthreads();
    int lq = t >> 3, sub = t & 7;
    int q = q0 + lq;
    float qx = px[q], qy = py[q], qz = pz[q];
    float sqn = __fadd_rn(__fadd_rn(__fmul_rn(qx, qx), __fmul_rn(qy, qy)), __fmul_rn(qz, qz));
    float dl[16];
    int il[16];
#pragma unroll
    for (int j = 0; j < 16; ++j) { dl[j] = INFINITY; il[j] = 0x7fffffff; }
    for (int m = sub; m < 2048; m += 8) {
        float mx = px[m], my = py[m], mz = pz[m];
        float sqm = __fadd_rn(__fadd_rn(__fmul_rn(mx, mx), __fmul_rn(my, my)), __fmul_rn(mz, mz));
        float dot = __fadd_rn(__fadd_rn(__fmul_rn(qx, mx), __fmul_rn(qy, my)), __fmul_rn(qz, mz));
        float d2 = __fsub_rn(__fadd_rn(sqn, sqm), __fmul_rn(2.0f, dot));
        if (d2 < dl[15]) {
#pragma unroll
            for (int j = 15; j >= 1; --j) {
                bool sh = d2 < dl[j - 1];
                float nd = sh ? dl[j - 1] : d2;
                int ni = sh ? il[j - 1] : m;
                bool up = d2 < dl[j];
                dl[j] = up ? nd : dl[j];
                il[j] = up ? ni : il[j];
            }
            if (d2 < dl[0]) { dl[0] = d2; il[0] = m; }
        }
    }
#pragma unroll
    for (int j = 0; j < 16; ++j) { md[lq][sub][j] = dl[j]; mi[lq][sub][j] = il[j]; }
    __syncthreads();
    if (sub == 0) {
        int hh[8] = {0, 0, 0, 0, 0, 0, 0, 0};
        for (int j = 0; j < 16; ++j) {
            float bd = INFINITY;
            int bi = 0x7fffffff, bt = 0;
#pragma unroll
            for (int th = 0; th < 8; ++th) {
                bool ok = hh[th] < 16;
                float d = ok ? md[lq][th][hh[th]] : INFINITY;
                int ii = ok ? mi[lq][th][hh[th]] : 0x7fffffff;
                bool better = (d < bd) || (d == bd && ii < bi);
                bd = better ? d : bd;
                bi = better ? ii : bi;
                bt = better ? th : bt;
            }
            idx[(b * 2048 + q) * 16 + j] = bi;
            hh[bt]++;
        }
    }
}

// ---------------------------------------------------------------- precompute
// Q=Wds@Ws, R=Gds@Gs computed fp32, all MFMA weights emitted as hi/lo bf16.
__global__ __launch_bounds__(256) void precompute_kernel(
    const float* __restrict__ Win, const float* __restrict__ Wdin,
    const float* __restrict__ Ws, const float* __restrict__ Wds,
    const float* __restrict__ Gs, const float* __restrict__ Gds,
    const float* __restrict__ Wout,
    us* __restrict__ W1h, us* __restrict__ W1l,
    us* __restrict__ W2h, us* __restrict__ W2l,
    float* __restrict__ Wg, us* __restrict__ Woh, us* __restrict__ Wol,
    float* __restrict__ Mbuf, float* __restrict__ Gbuf) {
    __shared__ float row[128];
    int blk = blockIdx.x, t = threadIdx.x;
    if (blk < 512) {
        int l = blk >> 7, i = blk & 127;
        if (t < 128) row[t] = Wds[l * 16384 + i * 128 + t];
        __syncthreads();
        if (t < 128) {
            float acc = 0.f;
            for (int m = 0; m < 128; ++m) acc += row[m] * Ws[l * 16384 + m * 128 + t];
            wsplit(acc, W1h, W1l, (size_t)l * 32768 + (128 + i) * 128 + t);
            wsplit(Ws[l * 16384 + i * 128 + t], W1h, W1l, (size_t)l * 32768 + i * 128 + t);
        }
    } else if (blk < 1024) {
        int l = (blk - 512) >> 7, i = (blk - 512) & 127;
        if (t < 128) row[t] = Gds[l * 16384 + i * 128 + t];
        __syncthreads();
        float acc = 0.f;
        for (int m = 0; m < 128; ++m) acc += row[m] * Gs[l * 32768 + m * 256 + t];
        if (t < 128) {
            wsplit(acc, W2h, W2l, (size_t)l * 32768 + (128 + i) * 128 + t);
            wsplit(Gs[l * 32768 + i * 256 + t], W2h, W2l, (size_t)l * 32768 + i * 128 + t);
        } else {
            Wg[l * 32768 + (128 + i) * 128 + (t - 128)] = acc;
            Wg[l * 32768 + i * 128 + (t - 128)] = Gs[l * 32768 + i * 256 + t];
        }
    } else if (blk == 1024) {
        if (t < 128) {
            float a0 = 0.f, a1 = 0.f, a2 = 0.f;
            for (int m = 0; m < 128; ++m) {
                float w = Wdin[t * 128 + m];
                a0 += w * Win[m * 3];
                a1 += w * Win[m * 3 + 1];
                a2 += w * Win[m * 3 + 2];
            }
            Mbuf[t * 3] = a0; Mbuf[t * 3 + 1] = a1; Mbuf[t * 3 + 2] = a2;
        } else if (t < 137) {
            int qq = t - 128, a = qq / 3, bb = qq - 3 * a;
            float acc = 0.f;
            for (int m = 0; m < 128; ++m) acc += Win[m * 3 + a] * Win[m * 3 + bb];
            Gbuf[qq] = acc;
        }
    } else {  // Wout slices, blk = 1025+l
        int l = blk - 1025;
        for (int i = t; i < 16384; i += 256) {
            int r = i >> 7, j = i & 127;
            wsplit(Wout[r * 512 + l * 128 + j], Woh, Wol, (size_t)l * 16384 + r * 128 + j);
        }
    }
}

// ---------------------------------------------------------------- stage 1
__global__ __launch_bounds__(256) void stage1_kernel(
    const float* __restrict__ x, const int* __restrict__ idx,
    const float* __restrict__ Win, const float* __restrict__ Mbuf,
    const float* __restrict__ Gbuf, us* __restrict__ hhi, us* __restrict__ hlo) {
    __shared__ float Yb[2][16][10];
    __shared__ float Pb[2][16][6];
    int t = threadIdx.x;
    int blk = blockIdx.x;
    int b = blk >> 10, n0 = (blk & 1023) * 2;
    if (t < 32) {
        int pt = t >> 4, k = t & 15;
        int n = n0 + pt, gpt = b * 2048 + n;
        float pxv = x[b * 6144 + n], pyv = x[b * 6144 + 2048 + n], pzv = x[b * 6144 + 4096 + n];
        float pn = sqrtf(pxv * pxv + pyv * pyv + pzv * pzv);
        float inv = 1.f / fmaxf(pn, EPSV);
        float dx = pxv * inv, dy = pyv * inv, dz = pzv * inv;
        int m = idx[gpt * 16 + k];
        float qx = x[b * 6144 + m], qy = x[b * 6144 + 2048 + m], qz = x[b * 6144 + 4096 + m];
        float Y[9];
        Y[0] = dy * qz - dz * qy; Y[1] = dz * qx - dx * qz; Y[2] = dx * qy - dy * qx;
        Y[3] = qx - pxv; Y[4] = qy - pyv; Y[5] = qz - pzv;
        Y[6] = pxv; Y[7] = pyv; Y[8] = pzv;
        float P[6];
        P[0] = Y[0] * Y[0] + Y[1] * Y[1] + Y[2] * Y[2];
        P[1] = Y[0] * Y[3] + Y[1] * Y[4] + Y[2] * Y[5];
        P[2] = Y[0] * Y[6] + Y[1] * Y[7] + Y[2] * Y[8];
        P[3] = Y[3] * Y[3] + Y[4] * Y[4] + Y[5] * Y[5];
        P[4] = Y[3] * Y[6] + Y[4] * Y[7] + Y[5] * Y[8];
        P[5] = Y[6] * Y[6] + Y[7] * Y[7] + Y[8] * Y[8];
        float nv2 = Gbuf[0] * P[0] + Gbuf[4] * P[3] + Gbuf[8] * P[5] +
                    (Gbuf[1] + Gbuf[3]) * P[1] + (Gbuf[2] + Gbuf[6]) * P[2] +
                    (Gbuf[5] + Gbuf[7]) * P[4];
        float s = 1.f / fmaxf(sqrtf(nv2), EPSV);
#pragma unroll
        for (int j = 0; j < 9; ++j) Yb[pt][k][j] = Y[j];
        Yb[pt][k][9] = s;
#pragma unroll
        for (int j = 0; j < 6; ++j) Pb[pt][k][j] = P[j];
    }
    __syncthreads();
    int pt = t >> 7, h = t & 127;
    int n = n0 + pt;
    float w0 = Win[h * 3], w1 = Win[h * 3 + 1], w2 = Win[h * 3 + 2];
    float m0 = Mbuf[h * 3], m1 = Mbuf[h * 3 + 1], m2 = Mbuf[h * 3 + 2];
    float cA0 = w0 * m0, cA3 = w1 * m1, cA5 = w2 * m2;
    float cA1 = w0 * m1 + w1 * m0, cA2 = w0 * m2 + w2 * m0, cA4 = w1 * m2 + w2 * m1;
    float cR0 = m0 * m0, cR3 = m1 * m1, cR5 = m2 * m2;
    float cR1 = 2.f * m0 * m1, cR2 = 2.f * m0 * m2, cR4 = 2.f * m1 * m2;
    float base[3] = {0.f, 0.f, 0.f}, corr[3] = {0.f, 0.f, 0.f};
    for (int k = 0; k < 16; ++k) {
        const float* Y = Yb[pt][k];
        const float* P = Pb[pt][k];
        float s = Y[9];
        float a = cA0 * P[0] + cA1 * P[1] + cA2 * P[2] + cA3 * P[3] + cA4 * P[4] + cA5 * P[5];
        float r2 = cR0 * P[0] + cR1 * P[1] + cR2 * P[2] + cR3 * P[3] + cR4 * P[4] + cR5 * P[5];
        float r = sqrtf(fmaxf(r2, 0.f));
        float D = fmaxf(s * r, EPSV);
        float dot = s * s * a / D;
        float wc = fmaxf(-dot, 0.f) * s / D;
#pragma unroll
        for (int c = 0; c < 3; ++c) {
            float yb = w0 * Y[c] + w1 * Y[3 + c] + w2 * Y[6 + c];
            float ym = m0 * Y[c] + m1 * Y[3 + c] + m2 * Y[6 + c];
            base[c] += s * yb;
            corr[c] += wc * ym;
        }
    }
#pragma unroll
    for (int c = 0; c < 3; ++c)
        wsplit((base[c] + corr[c]) * (1.f / 16.f), hhi, hlo,
               (size_t)(b * 2048 + n) * 384 + c * 128 + h);
}

#define MFMA_BF16 __builtin_amdgcn_mfma_f32_16x16x32_bf16

// ---------------------------------------------------------------- layer GEMM (hi/lo MFMA)
// 512 threads / 8 waves, 16 points (48 cols), C(256x48), K=128. Wave wv owns
// rows [32wv,32wv+32): waves 0..3 = v-half, 4..7 = k-half. Fragments read
// straight from global; LDS only for the v/k epilogue exchange.
template <int MODE>
__global__ __launch_bounds__(512, 4) void layer_gemm_kernel(
    const us* __restrict__ Xhi, const us* __restrict__ Xlo,
    const us* __restrict__ Whi, const us* __restrict__ Wlo,
    const float* __restrict__ biasg,
    us* __restrict__ Hhi, us* __restrict__ Hlo, float* __restrict__ g) {
    __shared__ float ebuf[2 * 128 * 49];   // kbuf | vbuf (fp32)
    __shared__ float spt[16];
    int t = threadIdx.x;
    int blk = blockIdx.x;
    int b = blk >> 7, n0 = (blk & 127) * 16;
    size_t pbase = (size_t)(b * 2048 + n0);
    const us* xh = Xhi + pbase * 384;
    const us* xl = Xlo + pbase * 384;
    int lane = t & 63, wv = t >> 6;
    int r15 = lane & 15, quad = lane >> 4;
    int arow = 32 * wv + r15;

    f32x4 acc[2][3];
#pragma unroll
    for (int i = 0; i < 2; ++i)
#pragma unroll
        for (int j = 0; j < 3; ++j) acc[i][j] = (f32x4){0.f, 0.f, 0.f, 0.f};

#pragma unroll 2
    for (int kc4 = 0; kc4 < 4; ++kc4) {
        int ko = kc4 * 32 + quad * 8;
        short8 a0h = *(const short8*)(Whi + arow * 128 + ko);
        short8 a1h = *(const short8*)(Whi + (arow + 16) * 128 + ko);
        short8 a0l = *(const short8*)(Wlo + arow * 128 + ko);
        short8 a1l = *(const short8*)(Wlo + (arow + 16) * 128 + ko);
        short8 b0h = *(const short8*)(xh + r15 * 128 + ko);
        short8 b1h = *(const short8*)(xh + (r15 + 16) * 128 + ko);
        short8 b2h = *(const short8*)(xh + (r15 + 32) * 128 + ko);
        short8 b0l = *(const short8*)(xl + r15 * 128 + ko);
        short8 b1l = *(const short8*)(xl + (r15 + 16) * 128 + ko);
        short8 b2l = *(const short8*)(xl + (r15 + 32) * 128 + ko);
        acc[0][0] = MFMA_BF16(a0h, b0h, acc[0][0], 0, 0, 0);
        acc[0][1] = MFMA_BF16(a0h, b1h, acc[0][1], 0, 0, 0);
        acc[0][2] = MFMA_BF16(a0h, b2h, acc[0][2], 0, 0, 0);
        acc[1][0] = MFMA_BF16(a1h, b0h, acc[1][0], 0, 0, 0);
        acc[1][1] = MFMA_BF16(a1h, b1h, acc[1][1], 0, 0, 0);
        acc[1][2] = MFMA_BF16(a1h, b2h, acc[1][2], 0, 0, 0);
        acc[0][0] = MFMA_BF16(a0h, b0l, acc[0][0], 0, 0, 0);
        acc[0][1] = MFMA_BF16(a0h, b1l, acc[0][1], 0, 0, 0);
        acc[0][2] = MFMA_BF16(a0h, b2l, acc[0][2], 0, 0, 0);
        acc[1][0] = MFMA_BF16(a1h, b0l, acc[1][0], 0, 0, 0);
        acc[1][1] = MFMA_BF16(a1h, b1l, acc[1][1], 0, 0, 0);
        acc[1][2] = MFMA_BF16(a1h, b2l, acc[1][2], 0, 0, 0);
        acc[0][0] = MFMA_BF16(a0l, b0h, acc[0][0], 0, 0, 0);
        acc[0][1] = MFMA_BF16(a0l, b1h, acc[0][1], 0, 0, 0);
        acc[0][2] = MFMA_BF16(a0l, b2h, acc[0][2], 0, 0, 0);
        acc[1][0] = MFMA_BF16(a1l, b0h, acc[1][0], 0, 0, 0);
        acc[1][1] = MFMA_BF16(a1l, b1h, acc[1][1], 0, 0, 0);
        acc[1][2] = MFMA_BF16(a1l, b2h, acc[1][2], 0, 0, 0);
    }

    float* kbuf = ebuf;              // 128 x 49
    float* vbuf = ebuf + 128 * 49;   // 128 x 49
#pragma unroll
    for (int ti = 0; ti < 2; ++ti) {
        int grow0 = (2 * wv + ti) * 16 + quad * 4;
#pragma unroll
        for (int nt = 0; nt < 3; ++nt) {
            int col = nt * 16 + r15;
#pragma unroll
            for (int r = 0; r < 4; ++r) {
                int grow = grow0 + r;
                float val = acc[ti][nt][r];
                if (wv < 4) vbuf[grow * 49 + col] = val;
                else kbuf[(grow - 128) * 49 + col] = val;
            }
        }
    }
    __syncthreads();

    // per-point ||v||^2 over 384 elems: 32 threads per point
    {
        int p = t >> 5, sub = t & 31;
        float S = 0.f;
#pragma unroll
        for (int j = 0; j < 12; ++j) {
            int e = sub * 12 + j;
            int c = e >> 7, row = e & 127;
            float v = vbuf[row * 49 + 3 * p + c];
            if (MODE == 1) v += biasg[b * 768 + c * 256 + row];
            S += v * v;
        }
#pragma unroll
        for (int off = 16; off; off >>= 1) S += __shfl_down(S, off, 32);
        if (sub == 0) spt[p] = 1.f / fmaxf(sqrtf(S), EPSV);
    }
    __syncthreads();

    // activation + hi/lo output (+ g accumulation for MODE 0)
    {
        int row = t & 127, pg = t >> 7;
        float bv[3] = {0.f, 0.f, 0.f}, bk[3] = {0.f, 0.f, 0.f};
        if (MODE == 1) {
#pragma unroll
            for (int c = 0; c < 3; ++c) {
                bv[c] = biasg[b * 768 + c * 256 + row];
                bk[c] = biasg[b * 768 + c * 256 + 128 + row];
            }
        }
        float gsum[3] = {0.f, 0.f, 0.f};
#pragma unroll
        for (int pi = 0; pi < 4; ++pi) {
            int p = pg * 4 + pi;
            float s = spt[p];
            float vx = vbuf[row * 49 + 3 * p + 0] + bv[0];
            float vy = vbuf[row * 49 + 3 * p + 1] + bv[1];
            float vz = vbuf[row * 49 + 3 * p + 2] + bv[2];
            float kx = kbuf[row * 49 + 3 * p + 0] + bk[0];
            float ky = kbuf[row * 49 + 3 * p + 1] + bk[1];
            float kz = kbuf[row * 49 + 3 * p + 2] + bk[2];
            float kn = sqrtf(kx * kx + ky * ky + kz * kz);
            float D = fmaxf(s * kn, EPSV);
            float dot = s * s * (vx * kx + vy * ky + vz * kz) / D;
            float f = fmaxf(-dot, 0.f) * s / D;
            float o0 = s * vx + f * kx;
            float o1 = s * vy + f * ky;
            float o2 = s * vz + f * kz;
            size_t gp = (pbase + p) * 384;
            wsplit(o0, Hhi, Hlo, gp + row);
            wsplit(o1, Hhi, Hlo, gp + 128 + row);
            wsplit(o2, Hhi, Hlo, gp + 256 + row);
            if (MODE == 0) { gsum[0] += o0; gsum[1] += o1; gsum[2] += o2; }
        }
        if (MODE == 0) {
#pragma unroll
            for (int c = 0; c < 3; ++c)
                atomicAdd(&g[b * 384 + c * 128 + row], gsum[c]);
        }
    }
}

// ---------------------------------------------------------------- gbias
__global__ __launch_bounds__(256) void gbias_kernel(const float* __restrict__ g,
                                                    const float* __restrict__ Wgl,
                                                    float* __restrict__ biasbuf) {
    __shared__ float gl[384];
    int b = blockIdx.x, r = threadIdx.x;
    for (int i = r; i < 384; i += 256) gl[i] = g[b * 384 + i] * (1.f / 2048.f);
    __syncthreads();
    float accv[3] = {0.f, 0.f, 0.f};
    const float4* wr = (const float4*)&Wgl[r * 128];
    for (int j = 0; j < 32; ++j) {
        float4 w4 = wr[j];
#pragma unroll
        for (int c = 0; c < 3; ++c) {
            float4 g4 = *(const float4*)&gl[c * 128 + 4 * j];
            accv[c] += w4.x * g4.x + w4.y * g4.y + w4.z * g4.z + w4.w * g4.w;
        }
    }
#pragma unroll
    for (int c = 0; c < 3; ++c) biasbuf[b * 768 + c * 256 + r] = accv[c];
}

// ---------------------------------------------------------------- Wout GEMM (hi/lo MFMA)
// C(128x48); wave wv owns M-tile wv; zero LDS; fp32 RMW into acc.
__global__ __launch_bounds__(512, 4) void wout_gemm_kernel(
    const us* __restrict__ Xhi, const us* __restrict__ Xlo,
    const us* __restrict__ Whi, const us* __restrict__ Wlo,
    float* __restrict__ accb) {
    int t = threadIdx.x;
    int blk = blockIdx.x;
    int b = blk >> 7, n0 = (blk & 127) * 16;
    size_t pbase = (size_t)(b * 2048 + n0);
    const us* xh = Xhi + pbase * 384;
    const us* xl = Xlo + pbase * 384;
    int lane = t & 63, wv = t >> 6;
    int r15 = lane & 15, quad = lane >> 4;
    int arow = wv * 16 + r15;
    f32x4 acc[3];
#pragma unroll
    for (int j = 0; j < 3; ++j) acc[j] = (f32x4){0.f, 0.f, 0.f, 0.f};
#pragma unroll 2
    for (int kc4 = 0; kc4 < 4; ++kc4) {
        int ko = kc4 * 32 + quad * 8;
        short8 ah = *(const short8*)(Whi + arow * 128 + ko);
        short8 al = *(const short8*)(Wlo + arow * 128 + ko);
        short8 b0h = *(const short8*)(xh + r15 * 128 + ko);
        short8 b1h = *(const short8*)(xh + (r15 + 16) * 128 + ko);
        short8 b2h = *(const short8*)(xh + (r15 + 32) * 128 + ko);
        short8 b0l = *(const short8*)(xl + r15 * 128 + ko);
        short8 b1l = *(const short8*)(xl + (r15 + 16) * 128 + ko);
        short8 b2l = *(const short8*)(xl + (r15 + 32) * 128 + ko);
        acc[0] = MFMA_BF16(ah, b0h, acc[0], 0, 0, 0);
        acc[1] = MFMA_BF16(ah, b1h, acc[1], 0, 0, 0);
        acc[2] = MFMA_BF16(ah, b2h, acc[2], 0, 0, 0);
        acc[0] = MFMA_BF16(ah, b0l, acc[0], 0, 0, 0);
        acc[1] = MFMA_BF16(ah, b1l, acc[1], 0, 0, 0);
        acc[2] = MFMA_BF16(ah, b2l, acc[2], 0, 0, 0);
        acc[0] = MFMA_BF16(al, b0h, acc[0], 0, 0, 0);
        acc[1] = MFMA_BF16(al, b1h, acc[1], 0, 0, 0);
        acc[2] = MFMA_BF16(al, b2h, acc[2], 0, 0, 0);
    }
#pragma unroll
    for (int nt = 0; nt < 3; ++nt) {
        int col = nt * 16 + r15;
        int p = col / 3, c = col - 3 * p;
        size_t gp = (pbase + p) * 384 + c * 128 + wv * 16 + quad * 4;
        float4 old = *(const float4*)&accb[gp];
        old.x += acc[nt][0]; old.y += acc[nt][1];
        old.z += acc[nt][2]; old.w += acc[nt][3];
        *(float4*)&accb[gp] = old;
    }
}

// ---------------------------------------------------------------- transpose + mean
__global__ __launch_bounds__(256) void out_kernel(const float* __restrict__ acc,
                                                  float* __restrict__ out1,
                                                  float* __restrict__ out0) {
    __shared__ float tile[64][33];
    int b = blockIdx.z, n0 = blockIdx.x * 64, j0 = blockIdx.y * 32;
    int t = threadIdx.x;
#pragma unroll
    for (int r = 0; r < 8; ++r) {
        int nf = (t >> 5) + r * 8, jf = t & 31;
        tile[nf][jf] = acc[(size_t)(b * 2048 + n0 + nf) * 384 + j0 + jf];
    }
    __syncthreads();
#pragma unroll
    for (int r = 0; r < 8; ++r) {
        int jf = (t >> 6) + r * 4, nf = t & 63;
        int j = j0 + jf;
        int ridx = (j & 127) * 3 + (j >> 7);
        out1[((size_t)b * 384 + ridx) * 2048 + n0 + nf] = tile[nf][jf];
    }
    if (t < 32) {
        float s = 0.f;
#pragma unroll
        for (int n = 0; n < 64; ++n) s += tile[n][t];
        int j = j0 + t;
        int ridx = (j & 127) * 3 + (j >> 7);
        atomicAdd(&out0[b * 384 + ridx], s * (1.f / 2048.f));
    }
}

// ---------------------------------------------------------------- launch
extern "C" void kernel_launch(void* const* d_in, const int* in_sizes, int n_in,
                              void* d_out, int out_size, void* d_ws, size_t ws_size,
                              hipStream_t stream) {
    const float* x    = (const float*)d_in[0];
    const float* Win  = (const float*)d_in[1];
    const float* Wdin = (const float*)d_in[2];
    const float* Ws   = (const float*)d_in[3];
    const float* Wds  = (const float*)d_in[4];
    const float* Gs   = (const float*)d_in[5];
    const float* Gds  = (const float*)d_in[6];
    const float* Wout = (const float*)d_in[7];

    float* out0 = (float*)d_out;   // (B,CD,3) = 3072
    float* out1 = out0 + 3072;     // (B,CD,3,N)

    char* ws = (char*)d_ws;
    int* idx = (int*)ws;                            // 1 MB
    us* hAhi = (us*)(ws + (1 << 20));               // 6291456 bf16 each
    us* hAlo = hAhi + 6291456;
    us* hBhi = hAlo + 6291456;
    us* hBlo = hBhi + 6291456;
    float* acc = (float*)(hBlo + 6291456);          // 6291456 f32
    float* g = acc + 6291456;                       // 3072
    us* W1h = (us*)(g + 3072);                      // 131072 each
    us* W1l = W1h + 131072;
    us* W2h = W1l + 131072;
    us* W2l = W2h + 131072;
    us* Woh = W2l + 131072;                         // 65536 each
    us* Wol = Woh + 65536;
    float* Wg = (float*)(Wol + 65536);              // 131072 f32
    float* Mbuf = Wg + 131072;                      // 384
    float* Gbuf = Mbuf + 384;                       // 16
    float* biasbuf = Gbuf + 16;                     // 6144

    hipMemsetAsync(acc, 0, (size_t)6291456 * 4, stream);
    hipMemsetAsync(out0, 0, (size_t)3072 * 4, stream);

    knn_kernel<<<dim3(64, 8), 256, 0, stream>>>(x, idx);
    precompute_kernel<<<1029, 256, 0, stream>>>(Win, Wdin, Ws, Wds, Gs, Gds, Wout,
                                                W1h, W1l, W2h, W2l, Wg, Woh, Wol,
                                                Mbuf, Gbuf);
    stage1_kernel<<<8192, 256, 0, stream>>>(x, idx, Win, Mbuf, Gbuf, hAhi, hAlo);
    for (int l = 0; l < 4; ++l) {
        hipMemsetAsync(g, 0, (size_t)3072 * 4, stream);
        layer_gemm_kernel<0><<<1024, 512, 0, stream>>>(hAhi, hAlo, W1h + l * 32768,
                                                       W1l + l * 32768, nullptr,
                                                       hBhi, hBlo, g);
        gbias_kernel<<<8, 256, 0, stream>>>(g, Wg + l * 32768, biasbuf);
        layer_gemm_kernel<1><<<1024, 512, 0, stream>>>(hBhi, hBlo, W2h + l * 32768,
                                                       W2l + l * 32768, biasbuf,
                                                       hAhi, hAlo, nullptr);
        wout_gemm_kernel<<<1024, 512, 0, stream>>>(hAhi, hAlo, Woh + l * 16384,
                                                   Wol + l * 16384, acc);
    }
    out_kernel<<<dim3(32, 12, 8), 256, 0, stream>>>(acc, out1, out0);
}

// Round 6
// 803.307 us; speedup vs baseline: 4.1109x; 1.1304x over previous
//
#include <hip/hip_runtime.h>
#include <math.h>

// VecPointNet on MI355X, round 6: knn grid 2x + chunked staging; wout fused
// into layerB (LDS bf16 fragment stash); per-layer g memsets folded in.
// GEMMs remain double-bf16 (hi/lo) MFMA: W@X ~= Whi@Xhi + Whi@Xlo + Wlo@Xhi.

#define EPSV 1e-12f

typedef unsigned short us;
typedef unsigned long long u64;
typedef __attribute__((ext_vector_type(8))) short short8;
typedef __attribute__((ext_vector_type(4))) float f32x4;

__device__ __forceinline__ us f2bf(float f) {
    unsigned int u = __float_as_uint(f);
    unsigned int r = (u + 0x7FFFu + ((u >> 16) & 1u)) >> 16;
    return (us)r;
}
__device__ __forceinline__ float bf2f(us s) {
    return __uint_as_float(((unsigned int)s) << 16);
}
__device__ __forceinline__ void wsplit(float v, us* __restrict__ hi, us* __restrict__ lo,
                                       size_t o) {
    us h = f2bf(v);
    hi[o] = h;
    lo[o] = f2bf(v - bf2f(h));
}
// monotone (order-preserving incl. negatives) fp32 -> u32
__device__ __forceinline__ unsigned int fflip(float f) {
    unsigned int u = __float_as_uint(f);
    return (u & 0x80000000u) ? ~u : (u | 0x80000000u);
}

// ---------------------------------------------------------------- KNN
// 16 subs/query, 16 queries/block, 1024 blocks (4 waves/SIMD). Candidates
// staged in 256-pt LDS chunks. Same fp32 d2 arithmetic as numpy; per-sub
// sorted lists merged by packed (flip(d2), idx) u64 -> exact stable top-16.
__global__ __launch_bounds__(256) void knn_kernel(const float* __restrict__ x,
                                                  int* __restrict__ idx) {
    __shared__ float cx[256], cy[256], cz[256];
    __shared__ u64 ml[16][16][16];  // 32 KB
    int t = threadIdx.x;
    int b = blockIdx.y, q0 = blockIdx.x * 16;
    int lq = t >> 4, sub = t & 15;
    int q = q0 + lq;
    float qx = x[b * 6144 + q], qy = x[b * 6144 + 2048 + q], qz = x[b * 6144 + 4096 + q];
    float sqn = __fadd_rn(__fadd_rn(__fmul_rn(qx, qx), __fmul_rn(qy, qy)), __fmul_rn(qz, qz));
    float dl[16];
    int il[16];
#pragma unroll
    for (int j = 0; j < 16; ++j) { dl[j] = INFINITY; il[j] = 0x7fffffff; }
    for (int ch = 0; ch < 8; ++ch) {
        __syncthreads();
        cx[t] = x[b * 6144 + ch * 256 + t];
        cy[t] = x[b * 6144 + 2048 + ch * 256 + t];
        cz[t] = x[b * 6144 + 4096 + ch * 256 + t];
        __syncthreads();
        for (int jj = 0; jj < 16; ++jj) {
            int mm = sub + jj * 16;
            float mx = cx[mm], my = cy[mm], mz = cz[mm];
            float sqm = __fadd_rn(__fadd_rn(__fmul_rn(mx, mx), __fmul_rn(my, my)), __fmul_rn(mz, mz));
            float dot = __fadd_rn(__fadd_rn(__fmul_rn(qx, mx), __fmul_rn(qy, my)), __fmul_rn(qz, mz));
            float d2 = __fsub_rn(__fadd_rn(sqn, sqm), __fmul_rn(2.0f, dot));
            if (d2 < dl[15]) {
                int m = ch * 256 + mm;
#pragma unroll
                for (int j = 15; j >= 1; --j) {
                    bool sh = d2 < dl[j - 1];
                    float nd = sh ? dl[j - 1] : d2;
                    int ni = sh ? il[j - 1] : m;
                    bool up = d2 < dl[j];
                    dl[j] = up ? nd : dl[j];
                    il[j] = up ? ni : il[j];
                }
                if (d2 < dl[0]) { dl[0] = d2; il[0] = m; }
            }
        }
    }
#pragma unroll
    for (int j = 0; j < 16; ++j)
        ml[lq][sub][j] = (((u64)fflip(dl[j])) << 32) | (unsigned int)il[j];
    __syncthreads();
    if (sub == 0) {
        int hh[16];
#pragma unroll
        for (int th = 0; th < 16; ++th) hh[th] = 0;
        for (int j = 0; j < 16; ++j) {
            u64 bk = ~0ull;
            int bt = 0;
#pragma unroll
            for (int th = 0; th < 16; ++th) {
                u64 k = ml[lq][th][hh[th] & 15];
                bool better = (hh[th] < 16) && (k < bk);
                bk = better ? k : bk;
                bt = better ? th : bt;
            }
            idx[(b * 2048 + q) * 16 + j] = (int)(unsigned int)(bk & 0xffffffffull);
#pragma unroll
            for (int th = 0; th < 16; ++th) hh[th] += (th == bt) ? 1 : 0;
        }
    }
}

// ---------------------------------------------------------------- precompute
__global__ __launch_bounds__(256) void precompute_kernel(
    const float* __restrict__ Win, const float* __restrict__ Wdin,
    const float* __restrict__ Ws, const float* __restrict__ Wds,
    const float* __restrict__ Gs, const float* __restrict__ Gds,
    const float* __restrict__ Wout,
    us* __restrict__ W1h, us* __restrict__ W1l,
    us* __restrict__ W2h, us* __restrict__ W2l,
    float* __restrict__ Wg, us* __restrict__ Woh, us* __restrict__ Wol,
    float* __restrict__ Mbuf, float* __restrict__ Gbuf) {
    __shared__ float row[128];
    int blk = blockIdx.x, t = threadIdx.x;
    if (blk < 512) {
        int l = blk >> 7, i = blk & 127;
        if (t < 128) row[t] = Wds[l * 16384 + i * 128 + t];
        __syncthreads();
        if (t < 128) {
            float acc = 0.f;
            for (int m = 0; m < 128; ++m) acc += row[m] * Ws[l * 16384 + m * 128 + t];
            wsplit(acc, W1h, W1l, (size_t)l * 32768 + (128 + i) * 128 + t);
            wsplit(Ws[l * 16384 + i * 128 + t], W1h, W1l, (size_t)l * 32768 + i * 128 + t);
        }
    } else if (blk < 1024) {
        int l = (blk - 512) >> 7, i = (blk - 512) & 127;
        if (t < 128) row[t] = Gds[l * 16384 + i * 128 + t];
        __syncthreads();
        float acc = 0.f;
        for (int m = 0; m < 128; ++m) acc += row[m] * Gs[l * 32768 + m * 256 + t];
        if (t < 128) {
            wsplit(acc, W2h, W2l, (size_t)l * 32768 + (128 + i) * 128 + t);
            wsplit(Gs[l * 32768 + i * 256 + t], W2h, W2l, (size_t)l * 32768 + i * 128 + t);
        } else {
            Wg[l * 32768 + (128 + i) * 128 + (t - 128)] = acc;
            Wg[l * 32768 + i * 128 + (t - 128)] = Gs[l * 32768 + i * 256 + t];
        }
    } else if (blk == 1024) {
        if (t < 128) {
            float a0 = 0.f, a1 = 0.f, a2 = 0.f;
            for (int m = 0; m < 128; ++m) {
                float w = Wdin[t * 128 + m];
                a0 += w * Win[m * 3];
                a1 += w * Win[m * 3 + 1];
                a2 += w * Win[m * 3 + 2];
            }
            Mbuf[t * 3] = a0; Mbuf[t * 3 + 1] = a1; Mbuf[t * 3 + 2] = a2;
        } else if (t < 137) {
            int qq = t - 128, a = qq / 3, bb = qq - 3 * a;
            float acc = 0.f;
            for (int m = 0; m < 128; ++m) acc += Win[m * 3 + a] * Win[m * 3 + bb];
            Gbuf[qq] = acc;
        }
    } else {  // Wout slices, blk = 1025+l
        int l = blk - 1025;
        for (int i = t; i < 16384; i += 256) {
            int r = i >> 7, j = i & 127;
            wsplit(Wout[r * 512 + l * 128 + j], Woh, Wol, (size_t)l * 16384 + r * 128 + j);
        }
    }
}

// ---------------------------------------------------------------- stage 1
__global__ __launch_bounds__(256) void stage1_kernel(
    const float* __restrict__ x, const int* __restrict__ idx,
    const float* __restrict__ Win, const float* __restrict__ Mbuf,
    const float* __restrict__ Gbuf, us* __restrict__ hhi, us* __restrict__ hlo) {
    __shared__ float Yb[2][16][10];
    __shared__ float Pb[2][16][6];
    int t = threadIdx.x;
    int blk = blockIdx.x;
    int b = blk >> 10, n0 = (blk & 1023) * 2;
    if (t < 32) {
        int pt = t >> 4, k = t & 15;
        int n = n0 + pt, gpt = b * 2048 + n;
        float pxv = x[b * 6144 + n], pyv = x[b * 6144 + 2048 + n], pzv = x[b * 6144 + 4096 + n];
        float pn = sqrtf(pxv * pxv + pyv * pyv + pzv * pzv);
        float inv = 1.f / fmaxf(pn, EPSV);
        float dx = pxv * inv, dy = pyv * inv, dz = pzv * inv;
        int m = idx[gpt * 16 + k];
        float qx = x[b * 6144 + m], qy = x[b * 6144 + 2048 + m], qz = x[b * 6144 + 4096 + m];
        float Y[9];
        Y[0] = dy * qz - dz * qy; Y[1] = dz * qx - dx * qz; Y[2] = dx * qy - dy * qx;
        Y[3] = qx - pxv; Y[4] = qy - pyv; Y[5] = qz - pzv;
        Y[6] = pxv; Y[7] = pyv; Y[8] = pzv;
        float P[6];
        P[0] = Y[0] * Y[0] + Y[1] * Y[1] + Y[2] * Y[2];
        P[1] = Y[0] * Y[3] + Y[1] * Y[4] + Y[2] * Y[5];
        P[2] = Y[0] * Y[6] + Y[1] * Y[7] + Y[2] * Y[8];
        P[3] = Y[3] * Y[3] + Y[4] * Y[4] + Y[5] * Y[5];
        P[4] = Y[3] * Y[6] + Y[4] * Y[7] + Y[5] * Y[8];
        P[5] = Y[6] * Y[6] + Y[7] * Y[7] + Y[8] * Y[8];
        float nv2 = Gbuf[0] * P[0] + Gbuf[4] * P[3] + Gbuf[8] * P[5] +
                    (Gbuf[1] + Gbuf[3]) * P[1] + (Gbuf[2] + Gbuf[6]) * P[2] +
                    (Gbuf[5] + Gbuf[7]) * P[4];
        float s = 1.f / fmaxf(sqrtf(nv2), EPSV);
#pragma unroll
        for (int j = 0; j < 9; ++j) Yb[pt][k][j] = Y[j];
        Yb[pt][k][9] = s;
#pragma unroll
        for (int j = 0; j < 6; ++j) Pb[pt][k][j] = P[j];
    }
    __syncthreads();
    int pt = t >> 7, h = t & 127;
    int n = n0 + pt;
    float w0 = Win[h * 3], w1 = Win[h * 3 + 1], w2 = Win[h * 3 + 2];
    float m0 = Mbuf[h * 3], m1 = Mbuf[h * 3 + 1], m2 = Mbuf[h * 3 + 2];
    float cA0 = w0 * m0, cA3 = w1 * m1, cA5 = w2 * m2;
    float cA1 = w0 * m1 + w1 * m0, cA2 = w0 * m2 + w2 * m0, cA4 = w1 * m2 + w2 * m1;
    float cR0 = m0 * m0, cR3 = m1 * m1, cR5 = m2 * m2;
    float cR1 = 2.f * m0 * m1, cR2 = 2.f * m0 * m2, cR4 = 2.f * m1 * m2;
    float base[3] = {0.f, 0.f, 0.f}, corr[3] = {0.f, 0.f, 0.f};
    for (int k = 0; k < 16; ++k) {
        const float* Y = Yb[pt][k];
        const float* P = Pb[pt][k];
        float s = Y[9];
        float a = cA0 * P[0] + cA1 * P[1] + cA2 * P[2] + cA3 * P[3] + cA4 * P[4] + cA5 * P[5];
        float r2 = cR0 * P[0] + cR1 * P[1] + cR2 * P[2] + cR3 * P[3] + cR4 * P[4] + cR5 * P[5];
        float r = sqrtf(fmaxf(r2, 0.f));
        float D = fmaxf(s * r, EPSV);
        float dot = s * s * a / D;
        float wc = fmaxf(-dot, 0.f) * s / D;
#pragma unroll
        for (int c = 0; c < 3; ++c) {
            float yb = w0 * Y[c] + w1 * Y[3 + c] + w2 * Y[6 + c];
            float ym = m0 * Y[c] + m1 * Y[3 + c] + m2 * Y[6 + c];
            base[c] += s * yb;
            corr[c] += wc * ym;
        }
    }
#pragma unroll
    for (int c = 0; c < 3; ++c)
        wsplit((base[c] + corr[c]) * (1.f / 16.f), hhi, hlo,
               (size_t)(b * 2048 + n) * 384 + c * 128 + h);
}

#define MFMA_BF16 __builtin_amdgcn_mfma_f32_16x16x32_bf16

// ---------------------------------------------------------------- layer A (hi/lo MFMA)
// 512 threads / 8 waves, 16 points (48 cols), C(256x48), K=128. Wave wv owns
// rows [32wv, 32wv+32): waves 0..3 = v-half, 4..7 = k-half. Fragments read
// straight from global; LDS only for the v/k epilogue exchange.
__global__ __launch_bounds__(512, 4) void layerA_kernel(
    const us* __restrict__ Xhi, const us* __restrict__ Xlo,
    const us* __restrict__ Whi, const us* __restrict__ Wlo,
    us* __restrict__ Hhi, us* __restrict__ Hlo, float* __restrict__ g) {
    __shared__ float ebuf[2 * 128 * 49];
    __shared__ float spt[16];
    int t = threadIdx.x;
    int blk = blockIdx.x;
    int b = blk >> 7, n0 = (blk & 127) * 16;
    size_t pbase = (size_t)(b * 2048 + n0);
    const us* xh = Xhi + pbase * 384;
    const us* xl = Xlo + pbase * 384;
    int lane = t & 63, wv = t >> 6;
    int r15 = lane & 15, quad = lane >> 4;
    int arow = 32 * wv + r15;

    f32x4 acc[2][3];
#pragma unroll
    for (int i = 0; i < 2; ++i)
#pragma unroll
        for (int j = 0; j < 3; ++j) acc[i][j] = (f32x4){0.f, 0.f, 0.f, 0.f};

#pragma unroll 2
    for (int kc4 = 0; kc4 < 4; ++kc4) {
        int ko = kc4 * 32 + quad * 8;
        short8 a0h = *(const short8*)(Whi + arow * 128 + ko);
        short8 a1h = *(const short8*)(Whi + (arow + 16) * 128 + ko);
        short8 a0l = *(const short8*)(Wlo + arow * 128 + ko);
        short8 a1l = *(const short8*)(Wlo + (arow + 16) * 128 + ko);
        short8 b0h = *(const short8*)(xh + r15 * 128 + ko);
        short8 b1h = *(const short8*)(xh + (r15 + 16) * 128 + ko);
        short8 b2h = *(const short8*)(xh + (r15 + 32) * 128 + ko);
        short8 b0l = *(const short8*)(xl + r15 * 128 + ko);
        short8 b1l = *(const short8*)(xl + (r15 + 16) * 128 + ko);
        short8 b2l = *(const short8*)(xl + (r15 + 32) * 128 + ko);
        acc[0][0] = MFMA_BF16(a0h, b0h, acc[0][0], 0, 0, 0);
        acc[0][1] = MFMA_BF16(a0h, b1h, acc[0][1], 0, 0, 0);
        acc[0][2] = MFMA_BF16(a0h, b2h, acc[0][2], 0, 0, 0);
        acc[1][0] = MFMA_BF16(a1h, b0h, acc[1][0], 0, 0, 0);
        acc[1][1] = MFMA_BF16(a1h, b1h, acc[1][1], 0, 0, 0);
        acc[1][2] = MFMA_BF16(a1h, b2h, acc[1][2], 0, 0, 0);
        acc[0][0] = MFMA_BF16(a0h, b0l, acc[0][0], 0, 0, 0);
        acc[0][1] = MFMA_BF16(a0h, b1l, acc[0][1], 0, 0, 0);
        acc[0][2] = MFMA_BF16(a0h, b2l, acc[0][2], 0, 0, 0);
        acc[1][0] = MFMA_BF16(a1h, b0l, acc[1][0], 0, 0, 0);
        acc[1][1] = MFMA_BF16(a1h, b1l, acc[1][1], 0, 0, 0);
        acc[1][2] = MFMA_BF16(a1h, b2l, acc[1][2], 0, 0, 0);
        acc[0][0] = MFMA_BF16(a0l, b0h, acc[0][0], 0, 0, 0);
        acc[0][1] = MFMA_BF16(a0l, b1h, acc[0][1], 0, 0, 0);
        acc[0][2] = MFMA_BF16(a0l, b2h, acc[0][2], 0, 0, 0);
        acc[1][0] = MFMA_BF16(a1l, b0h, acc[1][0], 0, 0, 0);
        acc[1][1] = MFMA_BF16(a1l, b1h, acc[1][1], 0, 0, 0);
        acc[1][2] = MFMA_BF16(a1l, b2h, acc[1][2], 0, 0, 0);
    }

    float* kbuf = ebuf;
    float* vbuf = ebuf + 128 * 49;
#pragma unroll
    for (int ti = 0; ti < 2; ++ti) {
        int grow0 = (2 * wv + ti) * 16 + quad * 4;
#pragma unroll
        for (int nt = 0; nt < 3; ++nt) {
            int col = nt * 16 + r15;
#pragma unroll
            for (int r = 0; r < 4; ++r) {
                int grow = grow0 + r;
                float val = acc[ti][nt][r];
                if (wv < 4) vbuf[grow * 49 + col] = val;
                else kbuf[(grow - 128) * 49 + col] = val;
            }
        }
    }
    __syncthreads();

    {
        int p = t >> 5, sub = t & 31;
        float S = 0.f;
#pragma unroll
        for (int j = 0; j < 12; ++j) {
            int e = sub * 12 + j;
            int c = e >> 7, row = e & 127;
            float v = vbuf[row * 49 + 3 * p + c];
            S += v * v;
        }
#pragma unroll
        for (int off = 16; off; off >>= 1) S += __shfl_down(S, off, 32);
        if (sub == 0) spt[p] = 1.f / fmaxf(sqrtf(S), EPSV);
    }
    __syncthreads();

    {
        int row = t & 127, pg = t >> 7;
        float gsum[3] = {0.f, 0.f, 0.f};
#pragma unroll
        for (int pi = 0; pi < 4; ++pi) {
            int p = pg * 4 + pi;
            float s = spt[p];
            float vx = vbuf[row * 49 + 3 * p + 0];
            float vy = vbuf[row * 49 + 3 * p + 1];
            float vz = vbuf[row * 49 + 3 * p + 2];
            float kx = kbuf[row * 49 + 3 * p + 0];
            float ky = kbuf[row * 49 + 3 * p + 1];
            float kz = kbuf[row * 49 + 3 * p + 2];
            float kn = sqrtf(kx * kx + ky * ky + kz * kz);
            float D = fmaxf(s * kn, EPSV);
            float dot = s * s * (vx * kx + vy * ky + vz * kz) / D;
            float f = fmaxf(-dot, 0.f) * s / D;
            float o0 = s * vx + f * kx;
            float o1 = s * vy + f * ky;
            float o2 = s * vz + f * kz;
            size_t gp = (pbase + p) * 384;
            wsplit(o0, Hhi, Hlo, gp + row);
            wsplit(o1, Hhi, Hlo, gp + 128 + row);
            wsplit(o2, Hhi, Hlo, gp + 256 + row);
            gsum[0] += o0; gsum[1] += o1; gsum[2] += o2;
        }
#pragma unroll
        for (int c = 0; c < 3; ++c)
            atomicAdd(&g[b * 384 + c * 128 + row], gsum[c]);
    }
}

// ---------------------------------------------------------------- gbias
__global__ __launch_bounds__(256) void gbias_kernel(const float* __restrict__ g,
                                                    const float* __restrict__ Wgl,
                                                    float* __restrict__ biasbuf) {
    __shared__ float gl[384];
    int b = blockIdx.x, r = threadIdx.x;
    for (int i = r; i < 384; i += 256) gl[i] = g[b * 384 + i] * (1.f / 2048.f);
    __syncthreads();
    float accv[3] = {0.f, 0.f, 0.f};
    const float4* wr = (const float4*)&Wgl[r * 128];
    for (int j = 0; j < 32; ++j) {
        float4 w4 = wr[j];
#pragma unroll
        for (int c = 0; c < 3; ++c) {
            float4 g4 = *(const float4*)&gl[c * 128 + 4 * j];
            accv[c] += w4.x * g4.x + w4.y * g4.y + w4.z * g4.z + w4.w * g4.w;
        }
    }
#pragma unroll
    for (int c = 0; c < 3; ++c) biasbuf[b * 768 + c * 256 + r] = accv[c];
}

// ---------------------------------------------------------------- layer B + Wout (fused)
// Same GEMM/epilogue as layerA (with per-batch bias), then h2's bf16 hi/lo
// fragments are stashed in the dead epilogue LDS (XOR-swizzled 16B chunks)
// and the Wout GEMM runs in-place, RMW into acc. Also zeroes g for the next
// layer (one block per batch).
__global__ __launch_bounds__(512, 4) void layerB_wout_kernel(
    const us* __restrict__ Xhi, const us* __restrict__ Xlo,
    const us* __restrict__ Whi, const us* __restrict__ Wlo,
    const float* __restrict__ biasg,
    const us* __restrict__ Woh, const us* __restrict__ Wol,
    us* __restrict__ Hhi, us* __restrict__ Hlo,
    float* __restrict__ accb, float* __restrict__ g) {
    __shared__ float ebuf[2 * 128 * 49];
    __shared__ float spt[16];
    int t = threadIdx.x;
    int blk = blockIdx.x;
    int b = blk >> 7, n0 = (blk & 127) * 16;
    size_t pbase = (size_t)(b * 2048 + n0);
    const us* xh = Xhi + pbase * 384;
    const us* xl = Xlo + pbase * 384;
    int lane = t & 63, wv = t >> 6;
    int r15 = lane & 15, quad = lane >> 4;
    int arow = 32 * wv + r15;

    f32x4 acc[2][3];
#pragma unroll
    for (int i = 0; i < 2; ++i)
#pragma unroll
        for (int j = 0; j < 3; ++j) acc[i][j] = (f32x4){0.f, 0.f, 0.f, 0.f};

#pragma unroll 2
    for (int kc4 = 0; kc4 < 4; ++kc4) {
        int ko = kc4 * 32 + quad * 8;
        short8 a0h = *(const short8*)(Whi + arow * 128 + ko);
        short8 a1h = *(const short8*)(Whi + (arow + 16) * 128 + ko);
        short8 a0l = *(const short8*)(Wlo + arow * 128 + ko);
        short8 a1l = *(const short8*)(Wlo + (arow + 16) * 128 + ko);
        short8 b0h = *(const short8*)(xh + r15 * 128 + ko);
        short8 b1h = *(const short8*)(xh + (r15 + 16) * 128 + ko);
        short8 b2h = *(const short8*)(xh + (r15 + 32) * 128 + ko);
        short8 b0l = *(const short8*)(xl + r15 * 128 + ko);
        short8 b1l = *(const short8*)(xl + (r15 + 16) * 128 + ko);
        short8 b2l = *(const short8*)(xl + (r15 + 32) * 128 + ko);
        acc[0][0] = MFMA_BF16(a0h, b0h, acc[0][0], 0, 0, 0);
        acc[0][1] = MFMA_BF16(a0h, b1h, acc[0][1], 0, 0, 0);
        acc[0][2] = MFMA_BF16(a0h, b2h, acc[0][2], 0, 0, 0);
        acc[1][0] = MFMA_BF16(a1h, b0h, acc[1][0], 0, 0, 0);
        acc[1][1] = MFMA_BF16(a1h, b1h, acc[1][1], 0, 0, 0);
        acc[1][2] = MFMA_BF16(a1h, b2h, acc[1][2], 0, 0, 0);
        acc[0][0] = MFMA_BF16(a0h, b0l, acc[0][0], 0, 0, 0);
        acc[0][1] = MFMA_BF16(a0h, b1l, acc[0][1], 0, 0, 0);
        acc[0][2] = MFMA_BF16(a0h, b2l, acc[0][2], 0, 0, 0);
        acc[1][0] = MFMA_BF16(a1h, b0l, acc[1][0], 0, 0, 0);
        acc[1][1] = MFMA_BF16(a1h, b1l, acc[1][1], 0, 0, 0);
        acc[1][2] = MFMA_BF16(a1h, b2l, acc[1][2], 0, 0, 0);
        acc[0][0] = MFMA_BF16(a0l, b0h, acc[0][0], 0, 0, 0);
        acc[0][1] = MFMA_BF16(a0l, b1h, acc[0][1], 0, 0, 0);
        acc[0][2] = MFMA_BF16(a0l, b2h, acc[0][2], 0, 0, 0);
        acc[1][0] = MFMA_BF16(a1l, b0h, acc[1][0], 0, 0, 0);
        acc[1][1] = MFMA_BF16(a1l, b1h, acc[1][1], 0, 0, 0);
        acc[1][2] = MFMA_BF16(a1l, b2h, acc[1][2], 0, 0, 0);
    }

    float* kbuf = ebuf;
    float* vbuf = ebuf + 128 * 49;
#pragma unroll
    for (int ti = 0; ti < 2; ++ti) {
        int grow0 = (2 * wv + ti) * 16 + quad * 4;
#pragma unroll
        for (int nt = 0; nt < 3; ++nt) {
            int col = nt * 16 + r15;
#pragma unroll
            for (int r = 0; r < 4; ++r) {
                int grow = grow0 + r;
                float val = acc[ti][nt][r];
                if (wv < 4) vbuf[grow * 49 + col] = val;
                else kbuf[(grow - 128) * 49 + col] = val;
            }
        }
    }
    __syncthreads();

    {
        int p = t >> 5, sub = t & 31;
        float S = 0.f;
#pragma unroll
        for (int j = 0; j < 12; ++j) {
            int e = sub * 12 + j;
            int c = e >> 7, row = e & 127;
            float v = vbuf[row * 49 + 3 * p + c] + biasg[b * 768 + c * 256 + row];
            S += v * v;
        }
#pragma unroll
        for (int off = 16; off; off >>= 1) S += __shfl_down(S, off, 32);
        if (sub == 0) spt[p] = 1.f / fmaxf(sqrtf(S), EPSV);
    }
    __syncthreads();

    // h2 epilogue: compute all o into registers (reading kbuf/vbuf), store
    // to global, then (after barrier) stash bf16 hi/lo fragments into ebuf.
    int row = t & 127, pg = t >> 7;
    us ohi[4][3], olo[4][3];
    {
        float bv[3], bk[3];
#pragma unroll
        for (int c = 0; c < 3; ++c) {
            bv[c] = biasg[b * 768 + c * 256 + row];
            bk[c] = biasg[b * 768 + c * 256 + 128 + row];
        }
#pragma unroll
        for (int pi = 0; pi < 4; ++pi) {
            int p = pg * 4 + pi;
            float s = spt[p];
            float vx = vbuf[row * 49 + 3 * p + 0] + bv[0];
            float vy = vbuf[row * 49 + 3 * p + 1] + bv[1];
            float vz = vbuf[row * 49 + 3 * p + 2] + bv[2];
            float kx = kbuf[row * 49 + 3 * p + 0] + bk[0];
            float ky = kbuf[row * 49 + 3 * p + 1] + bk[1];
            float kz = kbuf[row * 49 + 3 * p + 2] + bk[2];
            float kn = sqrtf(kx * kx + ky * ky + kz * kz);
            float D = fmaxf(s * kn, EPSV);
            float dot = s * s * (vx * kx + vy * ky + vz * kz) / D;
            float f = fmaxf(-dot, 0.f) * s / D;
            float o[3];
            o[0] = s * vx + f * kx;
            o[1] = s * vy + f * ky;
            o[2] = s * vz + f * kz;
            size_t gp = (pbase + p) * 384;
#pragma unroll
            for (int c = 0; c < 3; ++c) {
                us h = f2bf(o[c]);
                us l = f2bf(o[c] - bf2f(h));
                ohi[pi][c] = h; olo[pi][c] = l;
                Hhi[gp + c * 128 + row] = h;
                Hlo[gp + c * 128 + row] = l;
            }
        }
    }
    __syncthreads();  // all kbuf/vbuf reads done -> reuse ebuf for fragments

    us* xfh = (us*)ebuf;          // [col][swizzled k], 48*128
    us* xfl = xfh + 6144;
    {
        int chunk = row >> 3, off = row & 7;
#pragma unroll
        for (int pi = 0; pi < 4; ++pi) {
            int p = pg * 4 + pi;
#pragma unroll
            for (int c = 0; c < 3; ++c) {
                int col = p * 3 + c;
                int sw = (chunk ^ (col & 15)) * 8 + off;
                xfh[col * 128 + sw] = ohi[pi][c];
                xfl[col * 128 + sw] = olo[pi][c];
            }
        }
    }
    __syncthreads();

    // Wout GEMM: wave wv owns A-rows [16wv, 16wv+16)
    f32x4 wacc[3];
#pragma unroll
    for (int j = 0; j < 3; ++j) wacc[j] = (f32x4){0.f, 0.f, 0.f, 0.f};
    int warow = wv * 16 + r15;
#pragma unroll 2
    for (int kc4 = 0; kc4 < 4; ++kc4) {
        int ko = kc4 * 32 + quad * 8;
        short8 ah = *(const short8*)(Woh + warow * 128 + ko);
        short8 al = *(const short8*)(Wol + warow * 128 + ko);
        int cb = kc4 * 4 + quad;
        short8 bh[3], bl[3];
#pragma unroll
        for (int nt = 0; nt < 3; ++nt) {
            int col = nt * 16 + r15;
            int sw = (cb ^ (col & 15)) * 8;
            bh[nt] = *(const short8*)(xfh + col * 128 + sw);
            bl[nt] = *(const short8*)(xfl + col * 128 + sw);
        }
#pragma unroll
        for (int nt = 0; nt < 3; ++nt) {
            wacc[nt] = MFMA_BF16(ah, bh[nt], wacc[nt], 0, 0, 0);
            wacc[nt] = MFMA_BF16(ah, bl[nt], wacc[nt], 0, 0, 0);
            wacc[nt] = MFMA_BF16(al, bh[nt], wacc[nt], 0, 0, 0);
        }
    }
#pragma unroll
    for (int nt = 0; nt < 3; ++nt) {
        int col = nt * 16 + r15;
        int p = col / 3, c = col - 3 * p;
        size_t gp = (pbase + p) * 384 + c * 128 + wv * 16 + quad * 4;
        float4 old = *(const float4*)&accb[gp];
        old.x += wacc[nt][0]; old.y += wacc[nt][1];
        old.z += wacc[nt][2]; old.w += wacc[nt][3];
        *(float4*)&accb[gp] = old;
    }

    // zero g for the next layer (safe: this dispatch no longer reads g,
    // next layerA dispatch starts after this one completes)
    if ((blk & 127) == 0) {
        for (int i = t; i < 384; i += 512) g[b * 384 + i] = 0.f;
    }
}

// ---------------------------------------------------------------- transpose + mean
__global__ __launch_bounds__(256) void out_kernel(const float* __restrict__ acc,
                                                  float* __restrict__ out1,
                                                  float* __restrict__ out0) {
    __shared__ float tile[64][33];
    int b = blockIdx.z, n0 = blockIdx.x * 64, j0 = blockIdx.y * 32;
    int t = threadIdx.x;
#pragma unroll
    for (int r = 0; r < 8; ++r) {
        int nf = (t >> 5) + r * 8, jf = t & 31;
        tile[nf][jf] = acc[(size_t)(b * 2048 + n0 + nf) * 384 + j0 + jf];
    }
    __syncthreads();
#pragma unroll
    for (int r = 0; r < 8; ++r) {
        int jf = (t >> 6) + r * 4, nf = t & 63;
        int j = j0 + jf;
        int ridx = (j & 127) * 3 + (j >> 7);
        out1[((size_t)b * 384 + ridx) * 2048 + n0 + nf] = tile[nf][jf];
    }
    if (t < 32) {
        float s = 0.f;
#pragma unroll
        for (int n = 0; n < 64; ++n) s += tile[n][t];
        int j = j0 + t;
        int ridx = (j & 127) * 3 + (j >> 7);
        atomicAdd(&out0[b * 384 + ridx], s * (1.f / 2048.f));
    }
}

// ---------------------------------------------------------------- launch
extern "C" void kernel_launch(void* const* d_in, const int* in_sizes, int n_in,
                              void* d_out, int out_size, void* d_ws, size_t ws_size,
                              hipStream_t stream) {
    const float* x    = (const float*)d_in[0];
    const float* Win  = (const float*)d_in[1];
    const float* Wdin = (const float*)d_in[2];
    const float* Ws   = (const float*)d_in[3];
    const float* Wds  = (const float*)d_in[4];
    const float* Gs   = (const float*)d_in[5];
    const float* Gds  = (const float*)d_in[6];
    const float* Wout = (const float*)d_in[7];

    float* out0 = (float*)d_out;   // (B,CD,3) = 3072
    float* out1 = out0 + 3072;     // (B,CD,3,N)

    char* ws = (char*)d_ws;
    int* idx = (int*)ws;                            // 1 MB
    us* hAhi = (us*)(ws + (1 << 20));               // 6291456 bf16 each
    us* hAlo = hAhi + 6291456;
    us* hBhi = hAlo + 6291456;
    us* hBlo = hBhi + 6291456;
    float* acc = (float*)(hBlo + 6291456);          // 6291456 f32
    float* g = acc + 6291456;                       // 3072
    us* W1h = (us*)(g + 3072);                      // 131072 each
    us* W1l = W1h + 131072;
    us* W2h = W1l + 131072;
    us* W2l = W2h + 131072;
    us* Woh = W2l + 131072;                         // 65536 each
    us* Wol = Woh + 65536;
    float* Wg = (float*)(Wol + 65536);              // 131072 f32
    float* Mbuf = Wg + 131072;                      // 384
    float* Gbuf = Mbuf + 384;                       // 16
    float* biasbuf = Gbuf + 16;                     // 6144

    hipMemsetAsync(acc, 0, (size_t)6291456 * 4, stream);
    hipMemsetAsync(out0, 0, (size_t)3072 * 4, stream);
    hipMemsetAsync(g, 0, (size_t)3072 * 4, stream);

    knn_kernel<<<dim3(128, 8), 256, 0, stream>>>(x, idx);
    precompute_kernel<<<1029, 256, 0, stream>>>(Win, Wdin, Ws, Wds, Gs, Gds, Wout,
                                                W1h, W1l, W2h, W2l, Wg, Woh, Wol,
                                                Mbuf, Gbuf);
    stage1_kernel<<<8192, 256, 0, stream>>>(x, idx, Win, Mbuf, Gbuf, hAhi, hAlo);
    for (int l = 0; l < 4; ++l) {
        layerA_kernel<<<1024, 512, 0, stream>>>(hAhi, hAlo, W1h + l * 32768,
                                                W1l + l * 32768, hBhi, hBlo, g);
        gbias_kernel<<<8, 256, 0, stream>>>(g, Wg + l * 32768, biasbuf);
        layerB_wout_kernel<<<1024, 512, 0, stream>>>(hBhi, hBlo, W2h + l * 32768,
                                                     W2l + l * 32768, biasbuf,
                                                     Woh + l * 16384, Wol + l * 16384,
                                                     hAhi, hAlo, acc, g);
    }
    out_kernel<<<dim3(32, 12, 8), 256, 0, stream>>>(acc, out1, out0);
}